// Round 7
// baseline (1727.737 us; speedup 1.0000x reference)
//
#include <hip/hip_runtime.h>
#include <hip/hip_bf16.h>
#include <math.h>

#define NB 64
#define NBT 16
#define IMG 224
#define CIN 3
#define EMB 192
#define NHEADS 3
#define DEPTH 12
#define MLPD (4*EMB)
#define NPATCH 196
#define NTOK 197
#define M_TOK (NB*NTOK)      // 12608
#define M_PATCH (NB*NPATCH)  // 12544
#define SAT_H 8
#define SAT_DK 32
#define SAT_D 256
#define KPV 232              // P/Vt key-stride (bank-balanced, 16B-aligned)

typedef __attribute__((ext_vector_type(8))) short bf16x8;
typedef __attribute__((ext_vector_type(4))) float f32x4;
typedef __hip_bfloat16 bf16;

__device__ __forceinline__ float bf2f(ushort u) { return __uint_as_float(((unsigned)u) << 16); }
__device__ __forceinline__ ushort f2bf(float f) {
    bf16 h = __float2bfloat16(f);
    return *reinterpret_cast<ushort*>(&h);
}

// ---------------------------------------------------------------- stats, 2-stage
// stage 1: grid (16 chunks, 16 samples); partial sum/sumsq in double
__global__ __launch_bounds__(256) void stats1_kernel(const float* __restrict__ xg, double* __restrict__ part)
{
    int j = blockIdx.x, s = blockIdx.y;
    const float4* src = (const float4*)(xg + (size_t)s*(IMG*IMG)) + (size_t)j*784;
    double ls = 0.0, lq = 0.0;
    for (int i = threadIdx.x; i < 784; i += 256) {
        float4 v = src[i];
        double a = v.x, b = v.y, c = v.z, d = v.w;
        ls += a+b+c+d;
        lq += a*a + b*b + c*c + d*d;
    }
    __shared__ double ssum[256], ssq[256];
    ssum[threadIdx.x] = ls; ssq[threadIdx.x] = lq;
    __syncthreads();
    for (int st = 128; st > 0; st >>= 1) {
        if (threadIdx.x < st) { ssum[threadIdx.x] += ssum[threadIdx.x+st]; ssq[threadIdx.x] += ssq[threadIdx.x+st]; }
        __syncthreads();
    }
    if (threadIdx.x == 0) {
        part[(size_t)(s*16 + j)*2]     = ssum[0];
        part[(size_t)(s*16 + j)*2 + 1] = ssq[0];
    }
}

__global__ __launch_bounds__(64) void stats2_kernel(const double* __restrict__ part,
    const float* __restrict__ per_li, const float* __restrict__ per_li_var, int* __restrict__ idx_out)
{
    int s = blockIdx.x;
    if (threadIdx.x != 0) return;
    double sum = 0.0, sq = 0.0;
    for (int j = 0; j < 16; j++) { sum += part[(size_t)(s*16+j)*2]; sq += part[(size_t)(s*16+j)*2+1]; }
    double n = (double)(IMG*IMG);
    double mean = sum / n;
    double var  = (sq - n*mean*mean) / (n - 1.0);
    int i1 = 0, i2 = 0;
    for (int j = 0; j < 15; j++) {
        if ((double)per_li[j] < mean) i1++;
        if ((double)per_li_var[j] < var) i2++;
    }
    idx_out[s] = i1; idx_out[16 + s] = i2;
}

// ---------------------------------------------------------------- weight prep
// in [L][K][N] fp32 -> out [L][N][K] bf16
__global__ __launch_bounds__(256) void transpose_cast_kernel(const float* __restrict__ in,
    bf16* __restrict__ out, int K, int N)
{
    in  += (size_t)blockIdx.z*K*N;
    out += (size_t)blockIdx.z*N*K;
    __shared__ float t[32][33];
    int k0 = blockIdx.y*32, n0 = blockIdx.x*32;
    int tx = threadIdx.x & 31, ty = threadIdx.x >> 5;
    #pragma unroll
    for (int i = 0; i < 4; i++) {
        int k = ty + i*8;
        t[k][tx] = in[(size_t)(k0+k)*N + n0 + tx];
    }
    __syncthreads();
    #pragma unroll
    for (int i = 0; i < 4; i++) {
        int n = ty + i*8;
        out[(size_t)(n0+n)*K + k0 + tx] = __float2bfloat16(t[tx][n]);
    }
}

__global__ __launch_bounds__(256) void cast_kernel(const float* __restrict__ in, bf16* __restrict__ out, int n)
{
    int i = blockIdx.x*256 + threadIdx.x;
    if (i < n) out[i] = __float2bfloat16(in[i]);
}

__global__ __launch_bounds__(256) void concat3_kernel(const float* __restrict__ a,
    const float* __restrict__ b, const float* __restrict__ c, float* __restrict__ o)
{
    int i = blockIdx.x*256 + threadIdx.x;
    if (i < 256) o[i] = a[i];
    else if (i < 512) o[i] = b[i-256];
    else if (i < 768) o[i] = c[i-512];
}

// ---------------------------------------------------------------- im2col (bf16 out)
__global__ __launch_bounds__(256) void im2col_kernel(const float* __restrict__ x, bf16* __restrict__ out)
{
    int e = blockIdx.x*256 + threadIdx.x;
    if (e >= M_PATCH*768) return;
    int row = e / 768, col = e % 768;
    int b = row / NPATCH, p = row % NPATCH;
    int py = p / 14, px = p % 14;
    int c = col >> 8, r8 = col & 255;
    int i = r8 >> 4, j = r8 & 15;
    out[e] = __float2bfloat16(x[(((size_t)b*CIN + c)*IMG + py*16 + i)*IMG + px*16 + j]);
}

// ---------------------------------------------------------------- cls row (bf16)
__global__ void cls_kernel(const float* __restrict__ cls, const float* __restrict__ pos, bf16* __restrict__ tokb)
{
    int i = blockIdx.x*256 + threadIdx.x;
    if (i >= NB*EMB) return;
    int b = i / EMB, e = i % EMB;
    tokb[(size_t)(b*NTOK)*EMB + e] = __float2bfloat16(cls[e] + pos[e]);
}

// ---------------------------------------------------------------- MFMA bf16 GEMM
// C = A[M][K]bf16 @ Wt[N][K]bf16 (+epilogue). 64x64 tile, BK=64, 4 waves (2x2), 2x2 frags/wave.
// EPI: 0 none, 1 +bias*scale, 2 fp32 C += acc+bias, 3 gelu(acc+bias), 4 patch scatter,
//      5 V-transpose scatter into vT[(b*3+hd)*64+d][KPV]
template<int EPI, bool OBF>
__global__ __launch_bounds__(256) void mfma_gemm(
    const bf16* __restrict__ A, const bf16* __restrict__ Wt,
    const float* __restrict__ bias, const float* __restrict__ aux,
    void* __restrict__ Cv, int M, int N, int K, int ldc, float bias_scale)
{
    __shared__ bf16 As[64][72];
    __shared__ bf16 Bs[64][72];
    int tid = threadIdx.x;
    int wave = tid >> 6, lane = tid & 63;
    int wm = wave >> 1, wn = wave & 1;
    int m0 = blockIdx.y*64, n0 = blockIdx.x*64;
    f32x4 acc[2][2] = {};
    int sr = tid >> 3, sc = (tid & 7) * 8;

    for (int k0 = 0; k0 < K; k0 += 64) {
        #pragma unroll
        for (int it = 0; it < 2; it++) {
            int r = sr + it*32;
            *(uint4*)&As[r][sc] = *(const uint4*)(A  + (size_t)(m0 + r)*K + k0 + sc);
            *(uint4*)&Bs[r][sc] = *(const uint4*)(Wt + (size_t)(n0 + r)*K + k0 + sc);
        }
        __syncthreads();
        #pragma unroll
        for (int ks = 0; ks < 2; ks++) {
            int ko = ks*32 + (lane >> 4)*8;
            bf16x8 af[2], bfr[2];
            #pragma unroll
            for (int mi = 0; mi < 2; mi++) af[mi]  = *(const bf16x8*)&As[wm*32 + mi*16 + (lane & 15)][ko];
            #pragma unroll
            for (int ni = 0; ni < 2; ni++) bfr[ni] = *(const bf16x8*)&Bs[wn*32 + ni*16 + (lane & 15)][ko];
            #pragma unroll
            for (int mi = 0; mi < 2; mi++)
                #pragma unroll
                for (int ni = 0; ni < 2; ni++)
                    acc[mi][ni] = __builtin_amdgcn_mfma_f32_16x16x32_bf16(af[mi], bfr[ni], acc[mi][ni], 0, 0, 0);
        }
        __syncthreads();
    }
    #pragma unroll
    for (int mi = 0; mi < 2; mi++) {
        #pragma unroll
        for (int ni = 0; ni < 2; ni++) {
            int rbase = m0 + wm*32 + mi*16 + (lane >> 4)*4;
            int col   = n0 + wn*32 + ni*16 + (lane & 15);
            #pragma unroll
            for (int r = 0; r < 4; r++) {
                int row = rbase + r;
                float v = acc[mi][ni][r];
                if constexpr (EPI == 4) {
                    int b_ = row / NPATCH, p = row % NPATCH;
                    ((bf16*)Cv)[(size_t)(b_*NTOK + 1 + p)*EMB + col] =
                        __float2bfloat16(v + bias[col] + aux[(size_t)(1+p)*EMB + col]);
                } else if constexpr (EPI == 5) {
                    int hd = row >> 6, d = row & 63;
                    int bb = col / NTOK, t = col - bb*NTOK;
                    ((bf16*)Cv)[((size_t)((bb*3 + hd)*64 + d))*KPV + t] = __float2bfloat16(v);
                } else {
                    if constexpr (EPI == 1) v += bias[col]*bias_scale;
                    if constexpr (EPI == 2) v = ((float*)Cv)[(size_t)row*ldc + col] + v + bias[col];
                    if constexpr (EPI == 3) { v += bias[col]; v = 0.5f*v*(1.0f + erff(v*0.70710678118654752f)); }
                    if constexpr (OBF) ((bf16*)Cv)[(size_t)row*ldc + col] = __float2bfloat16(v);
                    else               ((float*)Cv)[(size_t)row*ldc + col] = v;
                }
            }
        }
    }
}

// ---------------------------------------------------------------- fused GEMM + LayerNorm
// Full-row tile: BM=64, N=192, 4 waves; wave w owns rows w*16..w*16+15 x all 192 cols (12 frags).
// v = (RESID? tokf : 0) + A@Wt + bias*bias_scale; tokf = v; hbB = bf16(LN(v; lnw, lnb)).
template<bool RESID>
__global__ __launch_bounds__(256) void mfma_gemm_ln(
    const bf16* __restrict__ A, const bf16* __restrict__ Wt,
    const float* __restrict__ bias, float bias_scale,
    const float* __restrict__ lnw, const float* __restrict__ lnb,
    float* __restrict__ tokf, bf16* __restrict__ hbB, int K)
{
    __shared__ bf16 As[64][72];
    __shared__ bf16 Bs[192][72];
    __shared__ float sB[192], sW[192], sLb[192];
    int tid = threadIdx.x;
    int m0 = blockIdx.x*64;
    if (tid < 192) { sB[tid] = bias[tid]*bias_scale; sW[tid] = lnw[tid]; sLb[tid] = lnb[tid]; }
    int wave = tid >> 6, lane = tid & 63;
    int qc = lane & 15, g = lane >> 4;
    f32x4 acc[12] = {};
    int sr = tid >> 3, sc = (tid & 7)*8;

    for (int k0 = 0; k0 < K; k0 += 64) {
        #pragma unroll
        for (int it = 0; it < 2; it++)
            *(uint4*)&As[sr + it*32][sc] = *(const uint4*)(A + (size_t)(m0 + sr + it*32)*K + k0 + sc);
        #pragma unroll
        for (int it = 0; it < 6; it++)
            *(uint4*)&Bs[sr + it*32][sc] = *(const uint4*)(Wt + (size_t)(sr + it*32)*K + k0 + sc);
        __syncthreads();
        #pragma unroll
        for (int ks = 0; ks < 2; ks++) {
            bf16x8 af = *(const bf16x8*)&As[wave*16 + qc][ks*32 + g*8];
            #pragma unroll
            for (int c = 0; c < 12; c++) {
                bf16x8 bf_ = *(const bf16x8*)&Bs[c*16 + qc][ks*32 + g*8];
                acc[c] = __builtin_amdgcn_mfma_f32_16x16x32_bf16(af, bf_, acc[c], 0, 0, 0);
            }
        }
        __syncthreads();
    }
    #pragma unroll
    for (int r = 0; r < 4; r++) {
        int row = m0 + wave*16 + g*4 + r;
        float v[12];
        float s = 0.f;
        #pragma unroll
        for (int c = 0; c < 12; c++) {
            int col = c*16 + qc;
            float t = acc[c][r] + sB[col];
            if constexpr (RESID) t += tokf[(size_t)row*EMB + col];
            v[c] = t; s += t;
        }
        #pragma unroll
        for (int o = 1; o < 16; o <<= 1) s += __shfl_xor(s, o);
        float mu = s * (1.0f/EMB);
        float ss = 0.f;
        #pragma unroll
        for (int c = 0; c < 12; c++) { float d = v[c]-mu; ss += d*d; }
        #pragma unroll
        for (int o = 1; o < 16; o <<= 1) ss += __shfl_xor(ss, o);
        float rsn = rsqrtf(ss*(1.0f/EMB) + 1e-5f);
        #pragma unroll
        for (int c = 0; c < 12; c++) {
            int col = c*16 + qc;
            tokf[(size_t)row*EMB + col] = v[c];
            hbB[(size_t)row*EMB + col] = __float2bfloat16((v[c]-mu)*rsn*sW[col] + sLb[col]);
        }
    }
}

// ---------------------------------------------------------------- SAT per-sample rows (fp32, tiny)
__global__ __launch_bounds__(256) void sat_rows_kernel(
    const float* __restrict__ eleva, const float* __restrict__ eleva_var,
    const float* __restrict__ wq, const float* __restrict__ bq,
    const float* __restrict__ wk, const float* __restrict__ bk,
    const float* __restrict__ wv, const float* __restrict__ bv,
    const int* __restrict__ idx, float* __restrict__ proj, float* __restrict__ sconst)
{
    int s = blockIdx.x;
    __shared__ float ev[2][EMB];
    __shared__ float pr[6][SAT_D];
    int t = threadIdx.x;
    for (int i = t; i < 2*EMB; i += 256) {
        if (i < EMB) ev[0][i] = eleva[(size_t)idx[s]*EMB + i];
        else         ev[1][i-EMB] = eleva_var[(size_t)idx[16+s]*EMB + (i-EMB)];
    }
    __syncthreads();
    for (int j = 0; j < 6; j++) {
        const float* vec = ev[(j >= 3) ? 1 : 0];
        const float* Wm = (j%3 == 0) ? wq : ((j%3 == 1) ? wk : wv);
        const float* bm = (j%3 == 0) ? bq : ((j%3 == 1) ? bk : bv);
        float accv = bm[t];
        for (int k = 0; k < EMB; k++) accv += vec[k]*Wm[(size_t)k*SAT_D + t];
        pr[j][t] = accv;
        proj[((size_t)s*6 + j)*SAT_D + t] = accv;
    }
    __syncthreads();
    if (t < 32) {
        int h = t >> 2, c = t & 3;
        const float* qv = pr[(c < 2) ? 0 : 3];
        const float* kv = pr[((c & 1) == 0) ? 1 : 4];
        float d = 0.f;
        for (int x = 0; x < SAT_DK; x++) d += qv[h*32+x]*kv[h*32+x];
        sconst[((size_t)s*8 + h)*4 + c] = d * 0.17677669529663687f;
    }
}

// ---------------------------------------------------------------- SAT main (per token, bf16 io)
__global__ __launch_bounds__(256) void sat_attn_kernel(
    const bf16* __restrict__ qkv0, const float* __restrict__ proj,
    const float* __restrict__ sconst, bf16* __restrict__ osum)
{
    int b = blockIdx.x;
    int s = b & 15;
    __shared__ float pr[6][SAT_D];
    __shared__ float sc[8][4];
    for (int i = threadIdx.x; i < 6*SAT_D; i += 256) pr[i >> 8][i & 255] = proj[(size_t)s*6*SAT_D + i];
    if (threadIdx.x < 32) sc[threadIdx.x >> 2][threadIdx.x & 3] = sconst[(size_t)s*32 + threadIdx.x];
    __syncthreads();
    int t = threadIdx.x;
    if (t >= NTOK) return;
    size_t m = (size_t)b*NTOK + t;
    const ushort* q0 = (const ushort*)(qkv0 + m*768);
    const ushort* k0 = q0 + 256;
    const ushort* v0 = q0 + 512;
    const float inv = 0.17677669529663687f;
    for (int h = 0; h < SAT_H; h++) {
        int d0 = h*32;
        float S00=0,S01=0,S02=0,S10=0,S20=0;
        #pragma unroll 8
        for (int d = 0; d < 32; d++) {
            float qv = bf2f(q0[d0+d]), kv = bf2f(k0[d0+d]);
            S00 += qv*kv;
            S01 += qv*pr[1][d0+d];
            S02 += qv*pr[4][d0+d];
            S10 += pr[0][d0+d]*kv;
            S20 += pr[3][d0+d]*kv;
        }
        S00*=inv; S01*=inv; S02*=inv; S10*=inv; S20*=inv;
        float al=0.f, be=0.f, ga=0.f;
        {
            float mx = fmaxf(S00, fmaxf(S01, S02));
            float e0 = expf(S00-mx), e1 = expf(S01-mx), e2 = expf(S02-mx);
            float is = 1.0f/(e0+e1+e2); al += e0*is; be += e1*is; ga += e2*is;
        }
        {
            float a1 = sc[h][0], a2 = sc[h][1];
            float mx = fmaxf(S10, fmaxf(a1, a2));
            float e0 = expf(S10-mx), e1 = expf(a1-mx), e2 = expf(a2-mx);
            float is = 1.0f/(e0+e1+e2); al += e0*is; be += e1*is; ga += e2*is;
        }
        {
            float a1 = sc[h][2], a2 = sc[h][3];
            float mx = fmaxf(S20, fmaxf(a1, a2));
            float e0 = expf(S20-mx), e1 = expf(a1-mx), e2 = expf(a2-mx);
            float is = 1.0f/(e0+e1+e2); al += e0*is; be += e1*is; ga += e2*is;
        }
        #pragma unroll 8
        for (int d = 0; d < 32; d++)
            osum[m*SAT_D + d0 + d] = __float2bfloat16(al*bf2f(v0[d0+d]) + be*pr[2][d0+d] + ga*pr[5][d0+d]);
    }
}

// ---------------------------------------------------------------- ViT attention: full MFMA
__global__ __launch_bounds__(256) void vit_attn_mfma(
    const bf16* __restrict__ qkv, const bf16* __restrict__ vT, bf16* __restrict__ hout)
{
    __shared__ ushort Ks[208*72];
    __shared__ ushort Vt[64*KPV];
    __shared__ ushort Pl[4][16*KPV];

    int u = (blockIdx.x & 7)*96 + (blockIdx.x >> 3);   // XCD-chunked: 8 crops per XCD
    int qg = u & 3, hd = (u >> 2) % 3, b = u / 12;
    int tid = threadIdx.x;
    size_t rowQ = (size_t)b*NTOK;

    for (int i = tid; i < 208*8; i += 256) {
        int k = i >> 3, c = i & 7;
        uint4 v = make_uint4(0u,0u,0u,0u);
        if (k < NTOK) v = *(const uint4*)(qkv + (rowQ + k)*384 + 192 + hd*64 + c*8);
        *(uint4*)&Ks[(size_t)k*72 + c*8] = v;
    }
    {
        const uint4* vsrc = (const uint4*)(vT + (size_t)((b*3 + hd)*64)*KPV);
        uint4* vdst = (uint4*)Vt;
        for (int i = tid; i < 64*KPV/8; i += 256) vdst[i] = vsrc[i];
    }
    __syncthreads();

    int wave = tid >> 6, lane = tid & 63;
    int qstart = (13*qg + 3) >> 2;
    int qcnt   = ((13*(qg+1) + 3) >> 2) - qstart;
    if (wave >= qcnt) return;
    int q0 = (qstart + wave)*16;
    int qcol = lane & 15, g = lane >> 4;

    bf16x8 qf[2] = {};
    if (q0 + qcol < NTOK) {
        const bf16* qp = qkv + (rowQ + q0 + qcol)*384 + hd*64 + g*8;
        qf[0] = *(const bf16x8*)qp;
        qf[1] = *(const bf16x8*)(qp + 32);
    }

    f32x4 st[13] = {};
    #pragma unroll
    for (int t = 0; t < 13; t++) {
        const ushort* krow = &Ks[(size_t)(16*t + qcol)*72];
        bf16x8 a0 = *(const bf16x8*)(krow + g*8);
        bf16x8 a1 = *(const bf16x8*)(krow + 32 + g*8);
        st[t] = __builtin_amdgcn_mfma_f32_16x16x32_bf16(a0, qf[0], st[t], 0, 0, 0);
        st[t] = __builtin_amdgcn_mfma_f32_16x16x32_bf16(a1, qf[1], st[t], 0, 0, 0);
    }

    const float scale = 0.125f;
    float mx = -1e30f;
    #pragma unroll
    for (int t = 0; t < 13; t++)
        #pragma unroll
        for (int r = 0; r < 4; r++) {
            int key = 16*t + 4*g + r;
            float s = st[t][r]*scale;
            st[t][r] = s;
            if (key < NTOK) mx = fmaxf(mx, s);
        }
    mx = fmaxf(mx, __shfl_xor(mx, 16));
    mx = fmaxf(mx, __shfl_xor(mx, 32));
    float sum = 0.f;
    #pragma unroll
    for (int t = 0; t < 13; t++)
        #pragma unroll
        for (int r = 0; r < 4; r++) {
            int key = 16*t + 4*g + r;
            float e = (key < NTOK) ? __expf(st[t][r] - mx) : 0.f;
            st[t][r] = e; sum += e;
        }
    sum += __shfl_xor(sum, 16);
    sum += __shfl_xor(sum, 32);
    float isv = 1.f/sum;

    ushort* P = Pl[wave];
    #pragma unroll
    for (int t = 0; t < 13; t++)
        #pragma unroll
        for (int r = 0; r < 4; r++)
            P[(size_t)qcol*KPV + 16*t + 4*g + r] = f2bf(st[t][r]*isv);
    #pragma unroll
    for (int r = 0; r < 4; r++)
        P[(size_t)qcol*KPV + 208 + 4*g + r] = 0;

    f32x4 oacc[4] = {};
    #pragma unroll
    for (int ks = 0; ks < 7; ks++) {
        bf16x8 pf = *(const bf16x8*)&P[(size_t)qcol*KPV + ks*32 + g*8];
        #pragma unroll
        for (int dt = 0; dt < 4; dt++) {
            bf16x8 vf = *(const bf16x8*)&Vt[(size_t)(dt*16 + qcol)*KPV + ks*32 + g*8];
            oacc[dt] = __builtin_amdgcn_mfma_f32_16x16x32_bf16(pf, vf, oacc[dt], 0, 0, 0);
        }
    }

    int nq = NTOK - q0; if (nq > 16) nq = 16;
    #pragma unroll
    for (int dt = 0; dt < 4; dt++)
        #pragma unroll
        for (int r = 0; r < 4; r++) {
            int q = 4*g + r;
            if (q < nq)
                hout[(rowQ + q0 + q)*EMB + hd*64 + dt*16 + qcol] = __float2bfloat16(oacc[dt][r]);
        }
}

// ---------------------------------------------------------------- final LN on t=0 rows only
__global__ __launch_bounds__(64) void final_ln_kernel(const float* __restrict__ tok,
    const float* __restrict__ w, const float* __restrict__ b_, float* __restrict__ out)
{
    int b = blockIdx.x, lane = threadIdx.x;
    const float* x = tok + (size_t)b*NTOK*EMB;
    float x0 = x[lane], x1 = x[lane+64], x2 = x[lane+128];
    float s = x0+x1+x2;
    for (int o = 32; o > 0; o >>= 1) s += __shfl_xor(s, o);
    float mu = s * (1.0f/EMB);
    float d0 = x0-mu, d1 = x1-mu, d2 = x2-mu;
    float ss = d0*d0 + d1*d1 + d2*d2;
    for (int o = 32; o > 0; o >>= 1) ss += __shfl_xor(ss, o);
    float rs = rsqrtf(ss*(1.0f/EMB) + 1e-5f);
    out[(size_t)b*EMB + lane]     = d0*rs*w[lane]     + b_[lane];
    out[(size_t)b*EMB + lane+64]  = d1*rs*w[lane+64]  + b_[lane+64];
    out[(size_t)b*EMB + lane+128] = d2*rs*w[lane+128] + b_[lane+128];
}

// ---------------------------------------------------------------- launch
extern "C" void kernel_launch(void* const* d_in, const int* in_sizes, int n_in,
                              void* d_out, int out_size, void* d_ws, size_t ws_size,
                              hipStream_t stream)
{
    const float* x          = (const float*)d_in[0];
    const float* xg         = (const float*)d_in[1];
    const float* per_li     = (const float*)d_in[2];
    const float* per_li_var = (const float*)d_in[3];
    const float* patch_w    = (const float*)d_in[4];
    const float* patch_b    = (const float*)d_in[5];
    const float* cls_token  = (const float*)d_in[6];
    const float* pos_embed  = (const float*)d_in[7];
    const float* eleva      = (const float*)d_in[8];
    const float* eleva_var  = (const float*)d_in[9];
    const float* sat_wq     = (const float*)d_in[10];
    const float* sat_bq     = (const float*)d_in[11];
    const float* sat_wk     = (const float*)d_in[12];
    const float* sat_bk     = (const float*)d_in[13];
    const float* sat_wv     = (const float*)d_in[14];
    const float* sat_bv     = (const float*)d_in[15];
    const float* sat_wo     = (const float*)d_in[16];
    const float* sat_bo     = (const float*)d_in[17];
    const float* ln1_w      = (const float*)d_in[18];
    const float* ln1_b      = (const float*)d_in[19];
    const float* qkv_w      = (const float*)d_in[20];
    const float* proj_w     = (const float*)d_in[21];
    const float* proj_b     = (const float*)d_in[22];
    const float* ln2_w      = (const float*)d_in[23];
    const float* ln2_b      = (const float*)d_in[24];
    const float* fc1_w      = (const float*)d_in[25];
    const float* fc1_b      = (const float*)d_in[26];
    const float* fc2_w      = (const float*)d_in[27];
    const float* fc2_b      = (const float*)d_in[28];
    const float* lnf_w      = (const float*)d_in[29];
    const float* lnf_b      = (const float*)d_in[30];
    float* out = (float*)d_out;

    char* p = (char*)d_ws;
    float* tokf = (float*)p;                 p += (size_t)M_TOK*EMB*4;
    bf16* hb    = (bf16*)p;                  p += (size_t)M_TOK*EMB*2;
    bf16* tokb  = (bf16*)p;                  p += (size_t)M_TOK*EMB*2;
    bf16* qkvb  = (bf16*)p;                  p += (size_t)M_TOK*768*2;
    bf16* osum  = (bf16*)p;                  p += (size_t)M_TOK*SAT_D*2;
    bf16* vTb   = (bf16*)p;                  p += (size_t)NB*3*64*KPV*2;
    bf16* qkv_wt  = (bf16*)p;                p += (size_t)DEPTH*576*EMB*2;
    bf16* proj_wt = (bf16*)p;                p += (size_t)DEPTH*EMB*EMB*2;
    bf16* fc1_wt  = (bf16*)p;                p += (size_t)DEPTH*MLPD*EMB*2;
    bf16* fc2_wt  = (bf16*)p;                p += (size_t)DEPTH*EMB*MLPD*2;
    bf16* patch_wb= (bf16*)p;                p += (size_t)EMB*768*2;
    bf16* sat_wqkvt = (bf16*)p;              p += (size_t)3*SAT_D*EMB*2;   // [768][192] = wq|wk|wv rows
    bf16* sat_wot = (bf16*)p;                p += (size_t)EMB*SAT_D*2;
    float* sat_bqkv = (float*)p;             p += 768*4;
    float* projb  = (float*)p;               p += 16*6*SAT_D*4;
    float* sconst = (float*)p;               p += 16*32*4;
    double* statp = (double*)p;              p += 256*2*8;
    int*   idxb   = (int*)p;

    // ---- weight prep (bf16, [N][K] transposed) ----
    transpose_cast_kernel<<<dim3(576/32, EMB/32, DEPTH), 256, 0, stream>>>(qkv_w,  qkv_wt,  EMB, 576);
    transpose_cast_kernel<<<dim3(EMB/32, EMB/32, DEPTH), 256, 0, stream>>>(proj_w, proj_wt, EMB, EMB);
    transpose_cast_kernel<<<dim3(MLPD/32, EMB/32, DEPTH), 256, 0, stream>>>(fc1_w, fc1_wt,  EMB, MLPD);
    transpose_cast_kernel<<<dim3(EMB/32, MLPD/32, DEPTH), 256, 0, stream>>>(fc2_w, fc2_wt,  MLPD, EMB);
    transpose_cast_kernel<<<dim3(SAT_D/32, EMB/32, 1), 256, 0, stream>>>(sat_wq, sat_wqkvt,              EMB, SAT_D);
    transpose_cast_kernel<<<dim3(SAT_D/32, EMB/32, 1), 256, 0, stream>>>(sat_wk, sat_wqkvt + 256*EMB,    EMB, SAT_D);
    transpose_cast_kernel<<<dim3(SAT_D/32, EMB/32, 1), 256, 0, stream>>>(sat_wv, sat_wqkvt + 512*EMB,    EMB, SAT_D);
    transpose_cast_kernel<<<dim3(EMB/32, SAT_D/32, 1), 256, 0, stream>>>(sat_wo, sat_wot, SAT_D, EMB);
    concat3_kernel<<<3, 256, 0, stream>>>(sat_bq, sat_bk, sat_bv, sat_bqkv);
    cast_kernel<<<(EMB*768 + 255)/256, 256, 0, stream>>>(patch_w, patch_wb, EMB*768);

    // ---- elevation stats (2-stage) ----
    stats1_kernel<<<dim3(16, 16), 256, 0, stream>>>(xg, statp);
    stats2_kernel<<<16, 64, 0, stream>>>(statp, per_li, per_li_var, idxb);
    // ---- patch embed ----
    im2col_kernel<<<(M_PATCH*768 + 255)/256, 256, 0, stream>>>(x, qkvb);
    mfma_gemm<4,true><<<dim3(EMB/64, M_PATCH/64), 256, 0, stream>>>(
        qkvb, patch_wb, patch_b, pos_embed, tokb, M_PATCH, EMB, 768, EMB, 1.0f);
    cls_kernel<<<(NB*EMB + 255)/256, 256, 0, stream>>>(cls_token, pos_embed, tokb);
    // ---- SAT ----
    sat_rows_kernel<<<16, 256, 0, stream>>>(eleva, eleva_var, sat_wq, sat_bq, sat_wk, sat_bk,
                                            sat_wv, sat_bv, idxb, projb, sconst);
    mfma_gemm<1,true><<<dim3(768/64, M_TOK/64), 256, 0, stream>>>(
        tokb, sat_wqkvt, sat_bqkv, nullptr, qkvb, M_TOK, 768, EMB, 768, 1.0f);
    sat_attn_kernel<<<NB, 256, 0, stream>>>(qkvb, projb, sconst, osum);
    // SAT output projection + first ln1, fused
    mfma_gemm_ln<false><<<M_TOK/64, 256, 0, stream>>>(
        osum, sat_wot, sat_bo, 3.0f, ln1_w, ln1_b, tokf, hb, SAT_D);
    // ---- ViT blocks ----
    for (int i = 0; i < DEPTH; i++) {
        // Q|K projection: [M][384]
        mfma_gemm<0,true><<<dim3(384/64, M_TOK/64), 256, 0, stream>>>(
            hb, qkv_wt + (size_t)i*576*EMB, nullptr, nullptr, qkvb, M_TOK, 384, EMB, 384, 1.0f);
        // V projection, transposed scatter
        mfma_gemm<5,true><<<dim3(M_TOK/64, EMB/64), 256, 0, stream>>>(
            qkv_wt + ((size_t)i*576 + 384)*EMB, hb, nullptr, nullptr, vTb, EMB, M_TOK, EMB, 0, 1.0f);
        vit_attn_mfma<<<768, 256, 0, stream>>>(qkvb, vTb, hb);
        // attn out proj + residual + ln2, fused
        mfma_gemm_ln<true><<<M_TOK/64, 256, 0, stream>>>(
            hb, proj_wt + (size_t)i*EMB*EMB, proj_b + i*EMB, 1.0f,
            ln2_w + i*EMB, ln2_b + i*EMB, tokf, hb, EMB);
        // fc1 + gelu
        mfma_gemm<3,true><<<dim3(MLPD/64, M_TOK/64), 256, 0, stream>>>(
            hb, fc1_wt + (size_t)i*MLPD*EMB, fc1_b + i*MLPD, nullptr, qkvb, M_TOK, MLPD, EMB, MLPD, 1.0f);
        if (i < DEPTH-1) {
            // fc2 + residual + next layer's ln1, fused
            mfma_gemm_ln<true><<<M_TOK/64, 256, 0, stream>>>(
                qkvb, fc2_wt + (size_t)i*EMB*MLPD, fc2_b + i*EMB, 1.0f,
                ln1_w + (i+1)*EMB, ln1_b + (i+1)*EMB, tokf, hb, MLPD);
        } else {
            mfma_gemm<2,false><<<dim3(EMB/64, M_TOK/64), 256, 0, stream>>>(
                qkvb, fc2_wt + (size_t)i*EMB*MLPD, fc2_b + i*EMB, nullptr, tokf, M_TOK, EMB, MLPD, EMB, 1.0f);
        }
    }
    final_ln_kernel<<<NB, 64, 0, stream>>>(tokf, lnf_w, lnf_b, out);
}

// Round 8
// 1383.356 us; speedup vs baseline: 1.2489x; 1.2489x over previous
//
#include <hip/hip_runtime.h>
#include <hip/hip_bf16.h>
#include <math.h>

#define NB 64
#define NBT 16
#define IMG 224
#define CIN 3
#define EMB 192
#define NHEADS 3
#define DEPTH 12
#define MLPD (4*EMB)
#define NPATCH 196
#define NTOK 197
#define M_TOK (NB*NTOK)      // 12608
#define M_PATCH (NB*NPATCH)  // 12544
#define SAT_H 8
#define SAT_DK 32
#define SAT_D 256
#define KPV 232              // P/Vt key-stride (bank-balanced, 16B-aligned)

typedef __attribute__((ext_vector_type(8))) short bf16x8;
typedef __attribute__((ext_vector_type(4))) float f32x4;
typedef __hip_bfloat16 bf16;

__device__ __forceinline__ float bf2f(ushort u) { return __uint_as_float(((unsigned)u) << 16); }
__device__ __forceinline__ ushort f2bf(float f) {
    bf16 h = __float2bfloat16(f);
    return *reinterpret_cast<ushort*>(&h);
}

// ---------------------------------------------------------------- stats, 2-stage
__global__ __launch_bounds__(256) void stats1_kernel(const float* __restrict__ xg, double* __restrict__ part)
{
    int j = blockIdx.x, s = blockIdx.y;
    const float4* src = (const float4*)(xg + (size_t)s*(IMG*IMG)) + (size_t)j*784;
    double ls = 0.0, lq = 0.0;
    for (int i = threadIdx.x; i < 784; i += 256) {
        float4 v = src[i];
        double a = v.x, b = v.y, c = v.z, d = v.w;
        ls += a+b+c+d;
        lq += a*a + b*b + c*c + d*d;
    }
    __shared__ double ssum[256], ssq[256];
    ssum[threadIdx.x] = ls; ssq[threadIdx.x] = lq;
    __syncthreads();
    for (int st = 128; st > 0; st >>= 1) {
        if (threadIdx.x < st) { ssum[threadIdx.x] += ssum[threadIdx.x+st]; ssq[threadIdx.x] += ssq[threadIdx.x+st]; }
        __syncthreads();
    }
    if (threadIdx.x == 0) {
        part[(size_t)(s*16 + j)*2]     = ssum[0];
        part[(size_t)(s*16 + j)*2 + 1] = ssq[0];
    }
}

__global__ __launch_bounds__(64) void stats2_kernel(const double* __restrict__ part,
    const float* __restrict__ per_li, const float* __restrict__ per_li_var, int* __restrict__ idx_out)
{
    int s = blockIdx.x;
    if (threadIdx.x != 0) return;
    double sum = 0.0, sq = 0.0;
    for (int j = 0; j < 16; j++) { sum += part[(size_t)(s*16+j)*2]; sq += part[(size_t)(s*16+j)*2+1]; }
    double n = (double)(IMG*IMG);
    double mean = sum / n;
    double var  = (sq - n*mean*mean) / (n - 1.0);
    int i1 = 0, i2 = 0;
    for (int j = 0; j < 15; j++) {
        if ((double)per_li[j] < mean) i1++;
        if ((double)per_li_var[j] < var) i2++;
    }
    idx_out[s] = i1; idx_out[16 + s] = i2;
}

// ---------------------------------------------------------------- weight prep
__global__ __launch_bounds__(256) void transpose_cast_kernel(const float* __restrict__ in,
    bf16* __restrict__ out, int K, int N)
{
    in  += (size_t)blockIdx.z*K*N;
    out += (size_t)blockIdx.z*N*K;
    __shared__ float t[32][33];
    int k0 = blockIdx.y*32, n0 = blockIdx.x*32;
    int tx = threadIdx.x & 31, ty = threadIdx.x >> 5;
    #pragma unroll
    for (int i = 0; i < 4; i++) {
        int k = ty + i*8;
        t[k][tx] = in[(size_t)(k0+k)*N + n0 + tx];
    }
    __syncthreads();
    #pragma unroll
    for (int i = 0; i < 4; i++) {
        int n = ty + i*8;
        out[(size_t)(n0+n)*K + k0 + tx] = __float2bfloat16(t[tx][n]);
    }
}

__global__ __launch_bounds__(256) void cast_kernel(const float* __restrict__ in, bf16* __restrict__ out, int n)
{
    int i = blockIdx.x*256 + threadIdx.x;
    if (i < n) out[i] = __float2bfloat16(in[i]);
}

__global__ __launch_bounds__(256) void concat3_kernel(const float* __restrict__ a,
    const float* __restrict__ b, const float* __restrict__ c, float* __restrict__ o)
{
    int i = blockIdx.x*256 + threadIdx.x;
    if (i < 256) o[i] = a[i];
    else if (i < 512) o[i] = b[i-256];
    else if (i < 768) o[i] = c[i-512];
}

// ---------------------------------------------------------------- im2col (bf16 out)
__global__ __launch_bounds__(256) void im2col_kernel(const float* __restrict__ x, bf16* __restrict__ out)
{
    int e = blockIdx.x*256 + threadIdx.x;
    if (e >= M_PATCH*768) return;
    int row = e / 768, col = e % 768;
    int b = row / NPATCH, p = row % NPATCH;
    int py = p / 14, px = p % 14;
    int c = col >> 8, r8 = col & 255;
    int i = r8 >> 4, j = r8 & 15;
    out[e] = __float2bfloat16(x[(((size_t)b*CIN + c)*IMG + py*16 + i)*IMG + px*16 + j]);
}

// ---------------------------------------------------------------- cls row (bf16)
__global__ void cls_kernel(const float* __restrict__ cls, const float* __restrict__ pos, bf16* __restrict__ tokb)
{
    int i = blockIdx.x*256 + threadIdx.x;
    if (i >= NB*EMB) return;
    int b = i / EMB, e = i % EMB;
    tokb[(size_t)(b*NTOK)*EMB + e] = __float2bfloat16(cls[e] + pos[e]);
}

// ---------------------------------------------------------------- MFMA bf16 GEMM
// C = A[M][K]bf16 @ Wt[N][K]bf16 (+epilogue). 64x64 tile, BK=64, 4 waves (2x2), 2x2 frags/wave.
// EPI: 0 none, 1 +bias*scale, 2 fp32 C += acc+bias, 3 gelu(acc+bias), 4 patch scatter,
//      5 V-transpose scatter into vT[(b*3+hd)*64+d][KPV]
template<int EPI, bool OBF>
__global__ __launch_bounds__(256) void mfma_gemm(
    const bf16* __restrict__ A, const bf16* __restrict__ Wt,
    const float* __restrict__ bias, const float* __restrict__ aux,
    void* __restrict__ Cv, int M, int N, int K, int ldc, float bias_scale)
{
    __shared__ bf16 As[64][72];
    __shared__ bf16 Bs[64][72];
    int tid = threadIdx.x;
    int wave = tid >> 6, lane = tid & 63;
    int wm = wave >> 1, wn = wave & 1;
    int m0 = blockIdx.y*64, n0 = blockIdx.x*64;
    f32x4 acc[2][2] = {};
    int sr = tid >> 3, sc = (tid & 7) * 8;

    for (int k0 = 0; k0 < K; k0 += 64) {
        #pragma unroll
        for (int it = 0; it < 2; it++) {
            int r = sr + it*32;
            *(uint4*)&As[r][sc] = *(const uint4*)(A  + (size_t)(m0 + r)*K + k0 + sc);
            *(uint4*)&Bs[r][sc] = *(const uint4*)(Wt + (size_t)(n0 + r)*K + k0 + sc);
        }
        __syncthreads();
        #pragma unroll
        for (int ks = 0; ks < 2; ks++) {
            int ko = ks*32 + (lane >> 4)*8;
            bf16x8 af[2], bfr[2];
            #pragma unroll
            for (int mi = 0; mi < 2; mi++) af[mi]  = *(const bf16x8*)&As[wm*32 + mi*16 + (lane & 15)][ko];
            #pragma unroll
            for (int ni = 0; ni < 2; ni++) bfr[ni] = *(const bf16x8*)&Bs[wn*32 + ni*16 + (lane & 15)][ko];
            #pragma unroll
            for (int mi = 0; mi < 2; mi++)
                #pragma unroll
                for (int ni = 0; ni < 2; ni++)
                    acc[mi][ni] = __builtin_amdgcn_mfma_f32_16x16x32_bf16(af[mi], bfr[ni], acc[mi][ni], 0, 0, 0);
        }
        __syncthreads();
    }
    #pragma unroll
    for (int mi = 0; mi < 2; mi++) {
        #pragma unroll
        for (int ni = 0; ni < 2; ni++) {
            int rbase = m0 + wm*32 + mi*16 + (lane >> 4)*4;
            int col   = n0 + wn*32 + ni*16 + (lane & 15);
            #pragma unroll
            for (int r = 0; r < 4; r++) {
                int row = rbase + r;
                float v = acc[mi][ni][r];
                if constexpr (EPI == 4) {
                    int b_ = row / NPATCH, p = row % NPATCH;
                    ((bf16*)Cv)[(size_t)(b_*NTOK + 1 + p)*EMB + col] =
                        __float2bfloat16(v + bias[col] + aux[(size_t)(1+p)*EMB + col]);
                } else if constexpr (EPI == 5) {
                    int hd = row >> 6, d = row & 63;
                    int bb = col / NTOK, t = col - bb*NTOK;
                    ((bf16*)Cv)[((size_t)((bb*3 + hd)*64 + d))*KPV + t] = __float2bfloat16(v);
                } else {
                    if constexpr (EPI == 1) v += bias[col]*bias_scale;
                    if constexpr (EPI == 2) v = ((float*)Cv)[(size_t)row*ldc + col] + v + bias[col];
                    if constexpr (EPI == 3) { v += bias[col]; v = 0.5f*v*(1.0f + erff(v*0.70710678118654752f)); }
                    if constexpr (OBF) ((bf16*)Cv)[(size_t)row*ldc + col] = __float2bfloat16(v);
                    else               ((float*)Cv)[(size_t)row*ldc + col] = v;
                }
            }
        }
    }
}

// ---------------------------------------------------------------- fused GEMM + LayerNorm, v2 (BM=16, grid 788)
// Block: 16 rows x 192 cols. 4 waves split cols: wave w owns cols w*48..w*48+47 (3 frags).
// Cross-wave LN combine via LDS (2 reduction rounds).
// v = (RESID? tokf : 0) + A@Wt + bias*bias_scale; tokf = v; hbB = bf16(LN(v)).
template<bool RESID>
__global__ __launch_bounds__(256) void mfma_gemm_ln(
    const bf16* __restrict__ A, const bf16* __restrict__ Wt,
    const float* __restrict__ bias, float bias_scale,
    const float* __restrict__ lnw, const float* __restrict__ lnb,
    float* __restrict__ tokf, bf16* __restrict__ hbB, int K)
{
    __shared__ bf16 As[16][72];
    __shared__ bf16 Bs[192][72];
    __shared__ float sB[192], sW[192], sLb[192];
    __shared__ float redS[4][16], redQ[4][16];
    int tid = threadIdx.x;
    int m0 = blockIdx.x*16;
    int wave = tid >> 6, lane = tid & 63;
    int qc = lane & 15, g = lane >> 4;
    if (tid < 192) { sB[tid] = bias[tid]*bias_scale; sW[tid] = lnw[tid]; sLb[tid] = lnb[tid]; }
    f32x4 acc[3] = {};
    int sr = tid >> 3, sc = (tid & 7)*8;

    for (int k0 = 0; k0 < K; k0 += 64) {
        if (tid < 128) {
            int r = tid >> 3, c = (tid & 7)*8;
            *(uint4*)&As[r][c] = *(const uint4*)(A + (size_t)(m0 + r)*K + k0 + c);
        }
        #pragma unroll
        for (int it = 0; it < 6; it++)
            *(uint4*)&Bs[sr + it*32][sc] = *(const uint4*)(Wt + (size_t)(sr + it*32)*K + k0 + sc);
        __syncthreads();
        #pragma unroll
        for (int ks = 0; ks < 2; ks++) {
            bf16x8 af = *(const bf16x8*)&As[qc][ks*32 + g*8];
            #pragma unroll
            for (int c = 0; c < 3; c++) {
                bf16x8 bf_ = *(const bf16x8*)&Bs[wave*48 + c*16 + qc][ks*32 + g*8];
                acc[c] = __builtin_amdgcn_mfma_f32_16x16x32_bf16(af, bf_, acc[c], 0, 0, 0);
            }
        }
        __syncthreads();
    }
    // lane holds rows m=4g+r (r=0..3) at cols wave*48 + c*16 + qc
    float v[3][4];
    #pragma unroll
    for (int c = 0; c < 3; c++) {
        int col = wave*48 + c*16 + qc;
        #pragma unroll
        for (int r = 0; r < 4; r++) {
            float t = acc[c][r] + sB[col];
            if constexpr (RESID) t += tokf[(size_t)(m0 + 4*g + r)*EMB + col];
            v[c][r] = t;
        }
    }
    // round 1: row sums
    #pragma unroll
    for (int r = 0; r < 4; r++) {
        float s = v[0][r] + v[1][r] + v[2][r];
        #pragma unroll
        for (int o = 1; o < 16; o <<= 1) s += __shfl_xor(s, o);
        if (qc == 0) redS[wave][4*g + r] = s;
    }
    __syncthreads();
    float mu[4];
    #pragma unroll
    for (int r = 0; r < 4; r++) {
        int m = 4*g + r;
        mu[r] = (redS[0][m] + redS[1][m] + redS[2][m] + redS[3][m]) * (1.0f/EMB);
    }
    // round 2: row sumsq around mu
    #pragma unroll
    for (int r = 0; r < 4; r++) {
        float d0 = v[0][r]-mu[r], d1 = v[1][r]-mu[r], d2 = v[2][r]-mu[r];
        float q = d0*d0 + d1*d1 + d2*d2;
        #pragma unroll
        for (int o = 1; o < 16; o <<= 1) q += __shfl_xor(q, o);
        if (qc == 0) redQ[wave][4*g + r] = q;
    }
    __syncthreads();
    float rstd[4];
    #pragma unroll
    for (int r = 0; r < 4; r++) {
        int m = 4*g + r;
        float q = redQ[0][m] + redQ[1][m] + redQ[2][m] + redQ[3][m];
        rstd[r] = rsqrtf(q*(1.0f/EMB) + 1e-5f);
    }
    #pragma unroll
    for (int c = 0; c < 3; c++) {
        int col = wave*48 + c*16 + qc;
        #pragma unroll
        for (int r = 0; r < 4; r++) {
            size_t idx = (size_t)(m0 + 4*g + r)*EMB + col;
            tokf[idx] = v[c][r];
            hbB[idx] = __float2bfloat16((v[c][r]-mu[r])*rstd[r]*sW[col] + sLb[col]);
        }
    }
}

// ---------------------------------------------------------------- SAT per-sample rows (fp32, tiny)
__global__ __launch_bounds__(256) void sat_rows_kernel(
    const float* __restrict__ eleva, const float* __restrict__ eleva_var,
    const float* __restrict__ wq, const float* __restrict__ bq,
    const float* __restrict__ wk, const float* __restrict__ bk,
    const float* __restrict__ wv, const float* __restrict__ bv,
    const int* __restrict__ idx, float* __restrict__ proj, float* __restrict__ sconst)
{
    int s = blockIdx.x;
    __shared__ float ev[2][EMB];
    __shared__ float pr[6][SAT_D];
    int t = threadIdx.x;
    for (int i = t; i < 2*EMB; i += 256) {
        if (i < EMB) ev[0][i] = eleva[(size_t)idx[s]*EMB + i];
        else         ev[1][i-EMB] = eleva_var[(size_t)idx[16+s]*EMB + (i-EMB)];
    }
    __syncthreads();
    for (int j = 0; j < 6; j++) {
        const float* vec = ev[(j >= 3) ? 1 : 0];
        const float* Wm = (j%3 == 0) ? wq : ((j%3 == 1) ? wk : wv);
        const float* bm = (j%3 == 0) ? bq : ((j%3 == 1) ? bk : bv);
        float accv = bm[t];
        for (int k = 0; k < EMB; k++) accv += vec[k]*Wm[(size_t)k*SAT_D + t];
        pr[j][t] = accv;
        proj[((size_t)s*6 + j)*SAT_D + t] = accv;
    }
    __syncthreads();
    if (t < 32) {
        int h = t >> 2, c = t & 3;
        const float* qv = pr[(c < 2) ? 0 : 3];
        const float* kv = pr[((c & 1) == 0) ? 1 : 4];
        float d = 0.f;
        for (int x = 0; x < SAT_DK; x++) d += qv[h*32+x]*kv[h*32+x];
        sconst[((size_t)s*8 + h)*4 + c] = d * 0.17677669529663687f;
    }
}

// ---------------------------------------------------------------- SAT main (per token, bf16 io)
__global__ __launch_bounds__(256) void sat_attn_kernel(
    const bf16* __restrict__ qkv0, const float* __restrict__ proj,
    const float* __restrict__ sconst, bf16* __restrict__ osum)
{
    int b = blockIdx.x;
    int s = b & 15;
    __shared__ float pr[6][SAT_D];
    __shared__ float sc[8][4];
    for (int i = threadIdx.x; i < 6*SAT_D; i += 256) pr[i >> 8][i & 255] = proj[(size_t)s*6*SAT_D + i];
    if (threadIdx.x < 32) sc[threadIdx.x >> 2][threadIdx.x & 3] = sconst[(size_t)s*32 + threadIdx.x];
    __syncthreads();
    int t = threadIdx.x;
    if (t >= NTOK) return;
    size_t m = (size_t)b*NTOK + t;
    const ushort* q0 = (const ushort*)(qkv0 + m*768);
    const ushort* k0 = q0 + 256;
    const ushort* v0 = q0 + 512;
    const float inv = 0.17677669529663687f;
    for (int h = 0; h < SAT_H; h++) {
        int d0 = h*32;
        float S00=0,S01=0,S02=0,S10=0,S20=0;
        #pragma unroll 8
        for (int d = 0; d < 32; d++) {
            float qv = bf2f(q0[d0+d]), kv = bf2f(k0[d0+d]);
            S00 += qv*kv;
            S01 += qv*pr[1][d0+d];
            S02 += qv*pr[4][d0+d];
            S10 += pr[0][d0+d]*kv;
            S20 += pr[3][d0+d]*kv;
        }
        S00*=inv; S01*=inv; S02*=inv; S10*=inv; S20*=inv;
        float al=0.f, be=0.f, ga=0.f;
        {
            float mx = fmaxf(S00, fmaxf(S01, S02));
            float e0 = expf(S00-mx), e1 = expf(S01-mx), e2 = expf(S02-mx);
            float is = 1.0f/(e0+e1+e2); al += e0*is; be += e1*is; ga += e2*is;
        }
        {
            float a1 = sc[h][0], a2 = sc[h][1];
            float mx = fmaxf(S10, fmaxf(a1, a2));
            float e0 = expf(S10-mx), e1 = expf(a1-mx), e2 = expf(a2-mx);
            float is = 1.0f/(e0+e1+e2); al += e0*is; be += e1*is; ga += e2*is;
        }
        {
            float a1 = sc[h][2], a2 = sc[h][3];
            float mx = fmaxf(S20, fmaxf(a1, a2));
            float e0 = expf(S20-mx), e1 = expf(a1-mx), e2 = expf(a2-mx);
            float is = 1.0f/(e0+e1+e2); al += e0*is; be += e1*is; ga += e2*is;
        }
        #pragma unroll 8
        for (int d = 0; d < 32; d++)
            osum[m*SAT_D + d0 + d] = __float2bfloat16(al*bf2f(v0[d0+d]) + be*pr[2][d0+d] + ga*pr[5][d0+d]);
    }
}

// ---------------------------------------------------------------- ViT attention: full MFMA
__global__ __launch_bounds__(256) void vit_attn_mfma(
    const bf16* __restrict__ qkv, const bf16* __restrict__ vT, bf16* __restrict__ hout)
{
    __shared__ ushort Ks[208*72];
    __shared__ ushort Vt[64*KPV];
    __shared__ ushort Pl[4][16*KPV];

    int u = (blockIdx.x & 7)*96 + (blockIdx.x >> 3);   // XCD-chunked: 8 crops per XCD
    int qg = u & 3, hd = (u >> 2) % 3, b = u / 12;
    int tid = threadIdx.x;
    size_t rowQ = (size_t)b*NTOK;

    for (int i = tid; i < 208*8; i += 256) {
        int k = i >> 3, c = i & 7;
        uint4 v = make_uint4(0u,0u,0u,0u);
        if (k < NTOK) v = *(const uint4*)(qkv + (rowQ + k)*384 + 192 + hd*64 + c*8);
        *(uint4*)&Ks[(size_t)k*72 + c*8] = v;
    }
    {
        const uint4* vsrc = (const uint4*)(vT + (size_t)((b*3 + hd)*64)*KPV);
        uint4* vdst = (uint4*)Vt;
        for (int i = tid; i < 64*KPV/8; i += 256) vdst[i] = vsrc[i];
    }
    __syncthreads();

    int wave = tid >> 6, lane = tid & 63;
    int qstart = (13*qg + 3) >> 2;
    int qcnt   = ((13*(qg+1) + 3) >> 2) - qstart;
    if (wave >= qcnt) return;
    int q0 = (qstart + wave)*16;
    int qcol = lane & 15, g = lane >> 4;

    bf16x8 qf[2] = {};
    if (q0 + qcol < NTOK) {
        const bf16* qp = qkv + (rowQ + q0 + qcol)*384 + hd*64 + g*8;
        qf[0] = *(const bf16x8*)qp;
        qf[1] = *(const bf16x8*)(qp + 32);
    }

    f32x4 st[13] = {};
    #pragma unroll
    for (int t = 0; t < 13; t++) {
        const ushort* krow = &Ks[(size_t)(16*t + qcol)*72];
        bf16x8 a0 = *(const bf16x8*)(krow + g*8);
        bf16x8 a1 = *(const bf16x8*)(krow + 32 + g*8);
        st[t] = __builtin_amdgcn_mfma_f32_16x16x32_bf16(a0, qf[0], st[t], 0, 0, 0);
        st[t] = __builtin_amdgcn_mfma_f32_16x16x32_bf16(a1, qf[1], st[t], 0, 0, 0);
    }

    const float scale = 0.125f;
    float mx = -1e30f;
    #pragma unroll
    for (int t = 0; t < 13; t++)
        #pragma unroll
        for (int r = 0; r < 4; r++) {
            int key = 16*t + 4*g + r;
            float s = st[t][r]*scale;
            st[t][r] = s;
            if (key < NTOK) mx = fmaxf(mx, s);
        }
    mx = fmaxf(mx, __shfl_xor(mx, 16));
    mx = fmaxf(mx, __shfl_xor(mx, 32));
    float sum = 0.f;
    #pragma unroll
    for (int t = 0; t < 13; t++)
        #pragma unroll
        for (int r = 0; r < 4; r++) {
            int key = 16*t + 4*g + r;
            float e = (key < NTOK) ? __expf(st[t][r] - mx) : 0.f;
            st[t][r] = e; sum += e;
        }
    sum += __shfl_xor(sum, 16);
    sum += __shfl_xor(sum, 32);
    float isv = 1.f/sum;

    ushort* P = Pl[wave];
    #pragma unroll
    for (int t = 0; t < 13; t++)
        #pragma unroll
        for (int r = 0; r < 4; r++)
            P[(size_t)qcol*KPV + 16*t + 4*g + r] = f2bf(st[t][r]*isv);
    #pragma unroll
    for (int r = 0; r < 4; r++)
        P[(size_t)qcol*KPV + 208 + 4*g + r] = 0;

    f32x4 oacc[4] = {};
    #pragma unroll
    for (int ks = 0; ks < 7; ks++) {
        bf16x8 pf = *(const bf16x8*)&P[(size_t)qcol*KPV + ks*32 + g*8];
        #pragma unroll
        for (int dt = 0; dt < 4; dt++) {
            bf16x8 vf = *(const bf16x8*)&Vt[(size_t)(dt*16 + qcol)*KPV + ks*32 + g*8];
            oacc[dt] = __builtin_amdgcn_mfma_f32_16x16x32_bf16(pf, vf, oacc[dt], 0, 0, 0);
        }
    }

    int nq = NTOK - q0; if (nq > 16) nq = 16;
    #pragma unroll
    for (int dt = 0; dt < 4; dt++)
        #pragma unroll
        for (int r = 0; r < 4; r++) {
            int q = 4*g + r;
            if (q < nq)
                hout[(rowQ + q0 + q)*EMB + hd*64 + dt*16 + qcol] = __float2bfloat16(oacc[dt][r]);
        }
}

// ---------------------------------------------------------------- final LN on t=0 rows only
__global__ __launch_bounds__(64) void final_ln_kernel(const float* __restrict__ tok,
    const float* __restrict__ w, const float* __restrict__ b_, float* __restrict__ out)
{
    int b = blockIdx.x, lane = threadIdx.x;
    const float* x = tok + (size_t)b*NTOK*EMB;
    float x0 = x[lane], x1 = x[lane+64], x2 = x[lane+128];
    float s = x0+x1+x2;
    for (int o = 32; o > 0; o >>= 1) s += __shfl_xor(s, o);
    float mu = s * (1.0f/EMB);
    float d0 = x0-mu, d1 = x1-mu, d2 = x2-mu;
    float ss = d0*d0 + d1*d1 + d2*d2;
    for (int o = 32; o > 0; o >>= 1) ss += __shfl_xor(ss, o);
    float rs = rsqrtf(ss*(1.0f/EMB) + 1e-5f);
    out[(size_t)b*EMB + lane]     = d0*rs*w[lane]     + b_[lane];
    out[(size_t)b*EMB + lane+64]  = d1*rs*w[lane+64]  + b_[lane+64];
    out[(size_t)b*EMB + lane+128] = d2*rs*w[lane+128] + b_[lane+128];
}

// ---------------------------------------------------------------- launch
extern "C" void kernel_launch(void* const* d_in, const int* in_sizes, int n_in,
                              void* d_out, int out_size, void* d_ws, size_t ws_size,
                              hipStream_t stream)
{
    const float* x          = (const float*)d_in[0];
    const float* xg         = (const float*)d_in[1];
    const float* per_li     = (const float*)d_in[2];
    const float* per_li_var = (const float*)d_in[3];
    const float* patch_w    = (const float*)d_in[4];
    const float* patch_b    = (const float*)d_in[5];
    const float* cls_token  = (const float*)d_in[6];
    const float* pos_embed  = (const float*)d_in[7];
    const float* eleva      = (const float*)d_in[8];
    const float* eleva_var  = (const float*)d_in[9];
    const float* sat_wq     = (const float*)d_in[10];
    const float* sat_bq     = (const float*)d_in[11];
    const float* sat_wk     = (const float*)d_in[12];
    const float* sat_bk     = (const float*)d_in[13];
    const float* sat_wv     = (const float*)d_in[14];
    const float* sat_bv     = (const float*)d_in[15];
    const float* sat_wo     = (const float*)d_in[16];
    const float* sat_bo     = (const float*)d_in[17];
    const float* ln1_w      = (const float*)d_in[18];
    const float* ln1_b      = (const float*)d_in[19];
    const float* qkv_w      = (const float*)d_in[20];
    const float* proj_w     = (const float*)d_in[21];
    const float* proj_b     = (const float*)d_in[22];
    const float* ln2_w      = (const float*)d_in[23];
    const float* ln2_b      = (const float*)d_in[24];
    const float* fc1_w      = (const float*)d_in[25];
    const float* fc1_b      = (const float*)d_in[26];
    const float* fc2_w      = (const float*)d_in[27];
    const float* fc2_b      = (const float*)d_in[28];
    const float* lnf_w      = (const float*)d_in[29];
    const float* lnf_b      = (const float*)d_in[30];
    float* out = (float*)d_out;

    char* p = (char*)d_ws;
    float* tokf = (float*)p;                 p += (size_t)M_TOK*EMB*4;
    bf16* hb    = (bf16*)p;                  p += (size_t)M_TOK*EMB*2;
    bf16* tokb  = (bf16*)p;                  p += (size_t)M_TOK*EMB*2;
    bf16* qkvb  = (bf16*)p;                  p += (size_t)M_TOK*768*2;
    bf16* osum  = (bf16*)p;                  p += (size_t)M_TOK*SAT_D*2;
    bf16* vTb   = (bf16*)p;                  p += (size_t)NB*3*64*KPV*2;
    bf16* qkv_wt  = (bf16*)p;                p += (size_t)DEPTH*576*EMB*2;
    bf16* proj_wt = (bf16*)p;                p += (size_t)DEPTH*EMB*EMB*2;
    bf16* fc1_wt  = (bf16*)p;                p += (size_t)DEPTH*MLPD*EMB*2;
    bf16* fc2_wt  = (bf16*)p;                p += (size_t)DEPTH*EMB*MLPD*2;
    bf16* patch_wb= (bf16*)p;                p += (size_t)EMB*768*2;
    bf16* sat_wqkvt = (bf16*)p;              p += (size_t)3*SAT_D*EMB*2;   // [768][192] = wq|wk|wv rows
    bf16* sat_wot = (bf16*)p;                p += (size_t)EMB*SAT_D*2;
    float* sat_bqkv = (float*)p;             p += 768*4;
    float* projb  = (float*)p;               p += 16*6*SAT_D*4;
    float* sconst = (float*)p;               p += 16*32*4;
    double* statp = (double*)p;              p += 256*2*8;
    int*   idxb   = (int*)p;

    // ---- weight prep (bf16, [N][K] transposed) ----
    transpose_cast_kernel<<<dim3(576/32, EMB/32, DEPTH), 256, 0, stream>>>(qkv_w,  qkv_wt,  EMB, 576);
    transpose_cast_kernel<<<dim3(EMB/32, EMB/32, DEPTH), 256, 0, stream>>>(proj_w, proj_wt, EMB, EMB);
    transpose_cast_kernel<<<dim3(MLPD/32, EMB/32, DEPTH), 256, 0, stream>>>(fc1_w, fc1_wt,  EMB, MLPD);
    transpose_cast_kernel<<<dim3(EMB/32, MLPD/32, DEPTH), 256, 0, stream>>>(fc2_w, fc2_wt,  MLPD, EMB);
    transpose_cast_kernel<<<dim3(SAT_D/32, EMB/32, 1), 256, 0, stream>>>(sat_wq, sat_wqkvt,              EMB, SAT_D);
    transpose_cast_kernel<<<dim3(SAT_D/32, EMB/32, 1), 256, 0, stream>>>(sat_wk, sat_wqkvt + 256*EMB,    EMB, SAT_D);
    transpose_cast_kernel<<<dim3(SAT_D/32, EMB/32, 1), 256, 0, stream>>>(sat_wv, sat_wqkvt + 512*EMB,    EMB, SAT_D);
    transpose_cast_kernel<<<dim3(EMB/32, SAT_D/32, 1), 256, 0, stream>>>(sat_wo, sat_wot, SAT_D, EMB);
    concat3_kernel<<<3, 256, 0, stream>>>(sat_bq, sat_bk, sat_bv, sat_bqkv);
    cast_kernel<<<(EMB*768 + 255)/256, 256, 0, stream>>>(patch_w, patch_wb, EMB*768);

    // ---- elevation stats (2-stage) ----
    stats1_kernel<<<dim3(16, 16), 256, 0, stream>>>(xg, statp);
    stats2_kernel<<<16, 64, 0, stream>>>(statp, per_li, per_li_var, idxb);
    // ---- patch embed ----
    im2col_kernel<<<(M_PATCH*768 + 255)/256, 256, 0, stream>>>(x, qkvb);
    mfma_gemm<4,true><<<dim3(EMB/64, M_PATCH/64), 256, 0, stream>>>(
        qkvb, patch_wb, patch_b, pos_embed, tokb, M_PATCH, EMB, 768, EMB, 1.0f);
    cls_kernel<<<(NB*EMB + 255)/256, 256, 0, stream>>>(cls_token, pos_embed, tokb);
    // ---- SAT ----
    sat_rows_kernel<<<16, 256, 0, stream>>>(eleva, eleva_var, sat_wq, sat_bq, sat_wk, sat_bk,
                                            sat_wv, sat_bv, idxb, projb, sconst);
    mfma_gemm<1,true><<<dim3(768/64, M_TOK/64), 256, 0, stream>>>(
        tokb, sat_wqkvt, sat_bqkv, nullptr, qkvb, M_TOK, 768, EMB, 768, 1.0f);
    sat_attn_kernel<<<NB, 256, 0, stream>>>(qkvb, projb, sconst, osum);
    // SAT output projection + first ln1, fused
    mfma_gemm_ln<false><<<M_TOK/16, 256, 0, stream>>>(
        osum, sat_wot, sat_bo, 3.0f, ln1_w, ln1_b, tokf, hb, SAT_D);
    // ---- ViT blocks ----
    for (int i = 0; i < DEPTH; i++) {
        // Q|K projection: [M][384]
        mfma_gemm<0,true><<<dim3(384/64, M_TOK/64), 256, 0, stream>>>(
            hb, qkv_wt + (size_t)i*576*EMB, nullptr, nullptr, qkvb, M_TOK, 384, EMB, 384, 1.0f);
        // V projection, transposed scatter
        mfma_gemm<5,true><<<dim3(M_TOK/64, EMB/64), 256, 0, stream>>>(
            qkv_wt + ((size_t)i*576 + 384)*EMB, hb, nullptr, nullptr, vTb, EMB, M_TOK, EMB, 0, 1.0f);
        vit_attn_mfma<<<768, 256, 0, stream>>>(qkvb, vTb, hb);
        // attn out proj + residual + ln2, fused
        mfma_gemm_ln<true><<<M_TOK/16, 256, 0, stream>>>(
            hb, proj_wt + (size_t)i*EMB*EMB, proj_b + i*EMB, 1.0f,
            ln2_w + i*EMB, ln2_b + i*EMB, tokf, hb, EMB);
        // fc1 + gelu
        mfma_gemm<3,true><<<dim3(MLPD/64, M_TOK/64), 256, 0, stream>>>(
            hb, fc1_wt + (size_t)i*MLPD*EMB, fc1_b + i*MLPD, nullptr, qkvb, M_TOK, MLPD, EMB, MLPD, 1.0f);
        if (i < DEPTH-1) {
            // fc2 + residual + next layer's ln1, fused
            mfma_gemm_ln<true><<<M_TOK/16, 256, 0, stream>>>(
                qkvb, fc2_wt + (size_t)i*EMB*MLPD, fc2_b + i*EMB, 1.0f,
                ln1_w + (i+1)*EMB, ln1_b + (i+1)*EMB, tokf, hb, MLPD);
        } else {
            mfma_gemm<2,false><<<dim3(EMB/64, M_TOK/64), 256, 0, stream>>>(
                qkvb, fc2_wt + (size_t)i*EMB*MLPD, fc2_b + i*EMB, nullptr, tokf, M_TOK, EMB, MLPD, EMB, 1.0f);
        }
    }
    final_ln_kernel<<<NB, 64, 0, stream>>>(tokf, lnf_w, lnf_b, out);
}

// Round 9
// 1353.014 us; speedup vs baseline: 1.2770x; 1.0224x over previous
//
#include <hip/hip_runtime.h>
#include <hip/hip_bf16.h>
#include <math.h>

#define NB 64
#define NBT 16
#define IMG 224
#define CIN 3
#define EMB 192
#define NHEADS 3
#define DEPTH 12
#define MLPD (4*EMB)
#define NPATCH 196
#define NTOK 197
#define M_TOK (NB*NTOK)      // 12608
#define M_PATCH (NB*NPATCH)  // 12544
#define SAT_H 8
#define SAT_DK 32
#define SAT_D 256
#define KPV 232              // P/Vt key-stride (bank-balanced, 16B-aligned)

typedef __attribute__((ext_vector_type(8))) short bf16x8;
typedef __attribute__((ext_vector_type(4))) float f32x4;
typedef __hip_bfloat16 bf16;

__device__ __forceinline__ float bf2f(ushort u) { return __uint_as_float(((unsigned)u) << 16); }
__device__ __forceinline__ ushort f2bf(float f) {
    bf16 h = __float2bfloat16(f);
    return *reinterpret_cast<ushort*>(&h);
}

// ---------------------------------------------------------------- stats, 2-stage
__global__ __launch_bounds__(256) void stats1_kernel(const float* __restrict__ xg, double* __restrict__ part)
{
    int j = blockIdx.x, s = blockIdx.y;
    const float4* src = (const float4*)(xg + (size_t)s*(IMG*IMG)) + (size_t)j*784;
    double ls = 0.0, lq = 0.0;
    for (int i = threadIdx.x; i < 784; i += 256) {
        float4 v = src[i];
        double a = v.x, b = v.y, c = v.z, d = v.w;
        ls += a+b+c+d;
        lq += a*a + b*b + c*c + d*d;
    }
    __shared__ double ssum[256], ssq[256];
    ssum[threadIdx.x] = ls; ssq[threadIdx.x] = lq;
    __syncthreads();
    for (int st = 128; st > 0; st >>= 1) {
        if (threadIdx.x < st) { ssum[threadIdx.x] += ssum[threadIdx.x+st]; ssq[threadIdx.x] += ssq[threadIdx.x+st]; }
        __syncthreads();
    }
    if (threadIdx.x == 0) {
        part[(size_t)(s*16 + j)*2]     = ssum[0];
        part[(size_t)(s*16 + j)*2 + 1] = ssq[0];
    }
}

__global__ __launch_bounds__(64) void stats2_kernel(const double* __restrict__ part,
    const float* __restrict__ per_li, const float* __restrict__ per_li_var, int* __restrict__ idx_out)
{
    int s = blockIdx.x;
    if (threadIdx.x != 0) return;
    double sum = 0.0, sq = 0.0;
    for (int j = 0; j < 16; j++) { sum += part[(size_t)(s*16+j)*2]; sq += part[(size_t)(s*16+j)*2+1]; }
    double n = (double)(IMG*IMG);
    double mean = sum / n;
    double var  = (sq - n*mean*mean) / (n - 1.0);
    int i1 = 0, i2 = 0;
    for (int j = 0; j < 15; j++) {
        if ((double)per_li[j] < mean) i1++;
        if ((double)per_li_var[j] < var) i2++;
    }
    idx_out[s] = i1; idx_out[16 + s] = i2;
}

// ---------------------------------------------------------------- merged weight prep (all transposes)
// job ranges over flat blockIdx.x; each block transposes one 32x32 tile [K][N]fp32 -> [N][K]bf16
__global__ __launch_bounds__(256) void prep_transpose_kernel(
    const float* __restrict__ qkv_w, const float* __restrict__ proj_w,
    const float* __restrict__ fc1_w, const float* __restrict__ fc2_w,
    const float* __restrict__ swq, const float* __restrict__ swk,
    const float* __restrict__ swv, const float* __restrict__ swo,
    bf16* __restrict__ qkv_wt, bf16* __restrict__ proj_wt,
    bf16* __restrict__ fc1_wt, bf16* __restrict__ fc2_wt,
    bf16* __restrict__ sat_wqkvt, bf16* __restrict__ sat_wot)
{
    int id = blockIdx.x;
    const float* in; bf16* outp; int K, N, r;
    if (id < 1296)      { int z = id/108,       rr = id%108; in = qkv_w  + (size_t)z*192*576; outp = qkv_wt  + (size_t)z*576*192; K=192; N=576; r = rr; }
    else if (id < 1728) { int z = (id-1296)/36, rr = (id-1296)%36; in = proj_w + (size_t)z*192*192; outp = proj_wt + (size_t)z*192*192; K=192; N=192; r = rr; }
    else if (id < 3456) { int z = (id-1728)/144, rr = (id-1728)%144; in = fc1_w + (size_t)z*192*768; outp = fc1_wt + (size_t)z*768*192; K=192; N=768; r = rr; }
    else if (id < 5184) { int z = (id-3456)/144, rr = (id-3456)%144; in = fc2_w + (size_t)z*768*192; outp = fc2_wt + (size_t)z*192*768; K=768; N=192; r = rr; }
    else if (id < 5232) { in = swq; outp = sat_wqkvt;            K=192; N=256; r = id-5184; }
    else if (id < 5280) { in = swk; outp = sat_wqkvt + 256*192;  K=192; N=256; r = id-5232; }
    else if (id < 5328) { in = swv; outp = sat_wqkvt + 512*192;  K=192; N=256; r = id-5280; }
    else                { in = swo; outp = sat_wot;              K=256; N=192; r = id-5328; }
    int nbx = N/32;
    int k0 = (r/nbx)*32, n0 = (r%nbx)*32;
    __shared__ float t[32][33];
    int tx = threadIdx.x & 31, ty = threadIdx.x >> 5;
    #pragma unroll
    for (int i = 0; i < 4; i++) t[ty + i*8][tx] = in[(size_t)(k0 + ty + i*8)*N + n0 + tx];
    __syncthreads();
    #pragma unroll
    for (int i = 0; i < 4; i++) outp[(size_t)(n0 + ty + i*8)*K + k0 + tx] = __float2bfloat16(t[tx][ty + i*8]);
}

__global__ __launch_bounds__(256) void cast_kernel(const float* __restrict__ in, bf16* __restrict__ out, int n)
{
    int i = blockIdx.x*256 + threadIdx.x;
    if (i < n) out[i] = __float2bfloat16(in[i]);
}

__global__ __launch_bounds__(256) void concat3_kernel(const float* __restrict__ a,
    const float* __restrict__ b, const float* __restrict__ c, float* __restrict__ o)
{
    int i = blockIdx.x*256 + threadIdx.x;
    if (i < 256) o[i] = a[i];
    else if (i < 512) o[i] = b[i-256];
    else if (i < 768) o[i] = c[i-512];
}

// ---------------------------------------------------------------- im2col (bf16 out)
__global__ __launch_bounds__(256) void im2col_kernel(const float* __restrict__ x, bf16* __restrict__ out)
{
    int e = blockIdx.x*256 + threadIdx.x;
    if (e >= M_PATCH*768) return;
    int row = e / 768, col = e % 768;
    int b = row / NPATCH, p = row % NPATCH;
    int py = p / 14, px = p % 14;
    int c = col >> 8, r8 = col & 255;
    int i = r8 >> 4, j = r8 & 15;
    out[e] = __float2bfloat16(x[(((size_t)b*CIN + c)*IMG + py*16 + i)*IMG + px*16 + j]);
}

// ---------------------------------------------------------------- cls row (bf16)
__global__ void cls_kernel(const float* __restrict__ cls, const float* __restrict__ pos, bf16* __restrict__ tokb)
{
    int i = blockIdx.x*256 + threadIdx.x;
    if (i >= NB*EMB) return;
    int b = i / EMB, e = i % EMB;
    tokb[(size_t)(b*NTOK)*EMB + e] = __float2bfloat16(cls[e] + pos[e]);
}

// ---------------------------------------------------------------- MFMA bf16 GEMM, BKC*64 K-columns staged per iteration
// C = A[M][K]bf16 @ Wt[N][K]bf16 (+epilogue). 64x64 tile, 4 waves (2x2), 2x2 frags/wave.
// EPI: 0 none, 1 +bias*scale, 2 fp32 C += acc+bias, 3 gelu(acc+bias), 4 patch scatter
template<int EPI, bool OBF, int BKC>
__global__ __launch_bounds__(256) void mfma_gemm(
    const bf16* __restrict__ A, const bf16* __restrict__ Wt,
    const float* __restrict__ bias, const float* __restrict__ aux,
    void* __restrict__ Cv, int M, int N, int K, int ldc, float bias_scale)
{
    __shared__ bf16 As[BKC][64][72];
    __shared__ bf16 Bs[BKC][64][72];
    int tid = threadIdx.x;
    int wave = tid >> 6, lane = tid & 63;
    int wm = wave >> 1, wn = wave & 1;
    int m0 = blockIdx.y*64, n0 = blockIdx.x*64;
    f32x4 acc[2][2] = {};
    int sr = tid >> 3, sc = (tid & 7) * 8;

    for (int k0 = 0; k0 < K; k0 += BKC*64) {
        #pragma unroll
        for (int c = 0; c < BKC; c++) {
            #pragma unroll
            for (int it = 0; it < 2; it++) {
                int r = sr + it*32;
                *(uint4*)&As[c][r][sc] = *(const uint4*)(A  + (size_t)(m0 + r)*K + k0 + c*64 + sc);
                *(uint4*)&Bs[c][r][sc] = *(const uint4*)(Wt + (size_t)(n0 + r)*K + k0 + c*64 + sc);
            }
        }
        __syncthreads();
        #pragma unroll
        for (int c = 0; c < BKC; c++) {
            #pragma unroll
            for (int ks = 0; ks < 2; ks++) {
                int ko = ks*32 + (lane >> 4)*8;
                bf16x8 af[2], bfr[2];
                #pragma unroll
                for (int mi = 0; mi < 2; mi++) af[mi]  = *(const bf16x8*)&As[c][wm*32 + mi*16 + (lane & 15)][ko];
                #pragma unroll
                for (int ni = 0; ni < 2; ni++) bfr[ni] = *(const bf16x8*)&Bs[c][wn*32 + ni*16 + (lane & 15)][ko];
                #pragma unroll
                for (int mi = 0; mi < 2; mi++)
                    #pragma unroll
                    for (int ni = 0; ni < 2; ni++)
                        acc[mi][ni] = __builtin_amdgcn_mfma_f32_16x16x32_bf16(af[mi], bfr[ni], acc[mi][ni], 0, 0, 0);
            }
        }
        __syncthreads();
    }
    #pragma unroll
    for (int mi = 0; mi < 2; mi++) {
        #pragma unroll
        for (int ni = 0; ni < 2; ni++) {
            int rbase = m0 + wm*32 + mi*16 + (lane >> 4)*4;
            int col   = n0 + wn*32 + ni*16 + (lane & 15);
            #pragma unroll
            for (int r = 0; r < 4; r++) {
                int row = rbase + r;
                float v = acc[mi][ni][r];
                if constexpr (EPI == 4) {
                    int b_ = row / NPATCH, p = row % NPATCH;
                    ((bf16*)Cv)[(size_t)(b_*NTOK + 1 + p)*EMB + col] =
                        __float2bfloat16(v + bias[col] + aux[(size_t)(1+p)*EMB + col]);
                } else {
                    if constexpr (EPI == 1) v += bias[col]*bias_scale;
                    if constexpr (EPI == 2) v = ((float*)Cv)[(size_t)row*ldc + col] + v + bias[col];
                    if constexpr (EPI == 3) { v += bias[col]; v = 0.5f*v*(1.0f + erff(v*0.70710678118654752f)); }
                    if constexpr (OBF) ((bf16*)Cv)[(size_t)row*ldc + col] = __float2bfloat16(v);
                    else               ((float*)Cv)[(size_t)row*ldc + col] = v;
                }
            }
        }
    }
}

// ---------------------------------------------------------------- merged QK-proj + V^T-proj (K=192, single-stage)
// blocks [0,1182): QK  C[M_TOK][384] = hb @ wqk^T;  [1182,1773): vT scatter = wv @ hb^T
__global__ __launch_bounds__(256) void qkv_proj_kernel(
    const bf16* __restrict__ hb, const bf16* __restrict__ wqk,
    const bf16* __restrict__ wv, bf16* __restrict__ qkvb, bf16* __restrict__ vTb)
{
    __shared__ bf16 As[3][64][72];
    __shared__ bf16 Bs[3][64][72];
    int id = blockIdx.x;
    bool isQK = id < 1182;
    const bf16 *Ap, *Bp; int m0, n0;
    if (isQK) { int bx = id % 6,  by = id / 6;          m0 = by*64; n0 = bx*64; Ap = hb; Bp = wqk; }
    else      { int id2 = id - 1182; int bx = id2 % 197, by = id2 / 197; m0 = by*64; n0 = bx*64; Ap = wv; Bp = hb; }
    int tid = threadIdx.x;
    int wave = tid >> 6, lane = tid & 63;
    int wm = wave >> 1, wn = wave & 1;
    f32x4 acc[2][2] = {};
    int sr = tid >> 3, sc = (tid & 7)*8;
    #pragma unroll
    for (int c = 0; c < 3; c++)
        #pragma unroll
        for (int it = 0; it < 2; it++) {
            int r = sr + it*32;
            *(uint4*)&As[c][r][sc] = *(const uint4*)(Ap + (size_t)(m0 + r)*192 + c*64 + sc);
            *(uint4*)&Bs[c][r][sc] = *(const uint4*)(Bp + (size_t)(n0 + r)*192 + c*64 + sc);
        }
    __syncthreads();
    #pragma unroll
    for (int c = 0; c < 3; c++)
        #pragma unroll
        for (int ks = 0; ks < 2; ks++) {
            int ko = ks*32 + (lane >> 4)*8;
            bf16x8 af[2], bfr[2];
            #pragma unroll
            for (int mi = 0; mi < 2; mi++) af[mi]  = *(const bf16x8*)&As[c][wm*32 + mi*16 + (lane & 15)][ko];
            #pragma unroll
            for (int ni = 0; ni < 2; ni++) bfr[ni] = *(const bf16x8*)&Bs[c][wn*32 + ni*16 + (lane & 15)][ko];
            #pragma unroll
            for (int mi = 0; mi < 2; mi++)
                #pragma unroll
                for (int ni = 0; ni < 2; ni++)
                    acc[mi][ni] = __builtin_amdgcn_mfma_f32_16x16x32_bf16(af[mi], bfr[ni], acc[mi][ni], 0, 0, 0);
        }
    #pragma unroll
    for (int mi = 0; mi < 2; mi++)
        #pragma unroll
        for (int ni = 0; ni < 2; ni++) {
            int rbase = m0 + wm*32 + mi*16 + (lane >> 4)*4;
            int col   = n0 + wn*32 + ni*16 + (lane & 15);
            #pragma unroll
            for (int r = 0; r < 4; r++) {
                int row = rbase + r;
                float v = acc[mi][ni][r];
                if (isQK) {
                    qkvb[(size_t)row*384 + col] = __float2bfloat16(v);
                } else {
                    int hd = row >> 6, d = row & 63;
                    int bb = col / NTOK, t = col - bb*NTOK;
                    vTb[((size_t)((bb*3 + hd)*64 + d))*KPV + t] = __float2bfloat16(v);
                }
            }
        }
}

// ---------------------------------------------------------------- fused GEMM + LayerNorm (BM=16, grid 788)
template<bool RESID>
__global__ __launch_bounds__(256) void mfma_gemm_ln(
    const bf16* __restrict__ A, const bf16* __restrict__ Wt,
    const float* __restrict__ bias, float bias_scale,
    const float* __restrict__ lnw, const float* __restrict__ lnb,
    float* __restrict__ tokf, bf16* __restrict__ hbB, int K)
{
    __shared__ bf16 As[16][72];
    __shared__ bf16 Bs[192][72];
    __shared__ float sB[192], sW[192], sLb[192];
    __shared__ float redS[4][16], redQ[4][16];
    int tid = threadIdx.x;
    int m0 = blockIdx.x*16;
    int wave = tid >> 6, lane = tid & 63;
    int qc = lane & 15, g = lane >> 4;
    if (tid < 192) { sB[tid] = bias[tid]*bias_scale; sW[tid] = lnw[tid]; sLb[tid] = lnb[tid]; }
    f32x4 acc[3] = {};
    int sr = tid >> 3, sc = (tid & 7)*8;

    for (int k0 = 0; k0 < K; k0 += 64) {
        if (tid < 128) {
            int r = tid >> 3, c = (tid & 7)*8;
            *(uint4*)&As[r][c] = *(const uint4*)(A + (size_t)(m0 + r)*K + k0 + c);
        }
        #pragma unroll
        for (int it = 0; it < 6; it++)
            *(uint4*)&Bs[sr + it*32][sc] = *(const uint4*)(Wt + (size_t)(sr + it*32)*K + k0 + sc);
        __syncthreads();
        #pragma unroll
        for (int ks = 0; ks < 2; ks++) {
            bf16x8 af = *(const bf16x8*)&As[qc][ks*32 + g*8];
            #pragma unroll
            for (int c = 0; c < 3; c++) {
                bf16x8 bf_ = *(const bf16x8*)&Bs[wave*48 + c*16 + qc][ks*32 + g*8];
                acc[c] = __builtin_amdgcn_mfma_f32_16x16x32_bf16(af, bf_, acc[c], 0, 0, 0);
            }
        }
        __syncthreads();
    }
    float v[3][4];
    #pragma unroll
    for (int c = 0; c < 3; c++) {
        int col = wave*48 + c*16 + qc;
        #pragma unroll
        for (int r = 0; r < 4; r++) {
            float t = acc[c][r] + sB[col];
            if constexpr (RESID) t += tokf[(size_t)(m0 + 4*g + r)*EMB + col];
            v[c][r] = t;
        }
    }
    #pragma unroll
    for (int r = 0; r < 4; r++) {
        float s = v[0][r] + v[1][r] + v[2][r];
        #pragma unroll
        for (int o = 1; o < 16; o <<= 1) s += __shfl_xor(s, o);
        if (qc == 0) redS[wave][4*g + r] = s;
    }
    __syncthreads();
    float mu[4];
    #pragma unroll
    for (int r = 0; r < 4; r++) {
        int m = 4*g + r;
        mu[r] = (redS[0][m] + redS[1][m] + redS[2][m] + redS[3][m]) * (1.0f/EMB);
    }
    #pragma unroll
    for (int r = 0; r < 4; r++) {
        float d0 = v[0][r]-mu[r], d1 = v[1][r]-mu[r], d2 = v[2][r]-mu[r];
        float q = d0*d0 + d1*d1 + d2*d2;
        #pragma unroll
        for (int o = 1; o < 16; o <<= 1) q += __shfl_xor(q, o);
        if (qc == 0) redQ[wave][4*g + r] = q;
    }
    __syncthreads();
    float rstd[4];
    #pragma unroll
    for (int r = 0; r < 4; r++) {
        int m = 4*g + r;
        float q = redQ[0][m] + redQ[1][m] + redQ[2][m] + redQ[3][m];
        rstd[r] = rsqrtf(q*(1.0f/EMB) + 1e-5f);
    }
    #pragma unroll
    for (int c = 0; c < 3; c++) {
        int col = wave*48 + c*16 + qc;
        #pragma unroll
        for (int r = 0; r < 4; r++) {
            size_t idx = (size_t)(m0 + 4*g + r)*EMB + col;
            tokf[idx] = v[c][r];
            hbB[idx] = __float2bfloat16((v[c][r]-mu[r])*rstd[r]*sW[col] + sLb[col]);
        }
    }
}

// ---------------------------------------------------------------- SAT per-sample rows (fp32, tiny)
__global__ __launch_bounds__(256) void sat_rows_kernel(
    const float* __restrict__ eleva, const float* __restrict__ eleva_var,
    const float* __restrict__ wq, const float* __restrict__ bq,
    const float* __restrict__ wk, const float* __restrict__ bk,
    const float* __restrict__ wv, const float* __restrict__ bv,
    const int* __restrict__ idx, float* __restrict__ proj, float* __restrict__ sconst)
{
    int s = blockIdx.x;
    __shared__ float ev[2][EMB];
    __shared__ float pr[6][SAT_D];
    int t = threadIdx.x;
    for (int i = t; i < 2*EMB; i += 256) {
        if (i < EMB) ev[0][i] = eleva[(size_t)idx[s]*EMB + i];
        else         ev[1][i-EMB] = eleva_var[(size_t)idx[16+s]*EMB + (i-EMB)];
    }
    __syncthreads();
    for (int j = 0; j < 6; j++) {
        const float* vec = ev[(j >= 3) ? 1 : 0];
        const float* Wm = (j%3 == 0) ? wq : ((j%3 == 1) ? wk : wv);
        const float* bm = (j%3 == 0) ? bq : ((j%3 == 1) ? bk : bv);
        float accv = bm[t];
        for (int k = 0; k < EMB; k++) accv += vec[k]*Wm[(size_t)k*SAT_D + t];
        pr[j][t] = accv;
        proj[((size_t)s*6 + j)*SAT_D + t] = accv;
    }
    __syncthreads();
    if (t < 32) {
        int h = t >> 2, c = t & 3;
        const float* qv = pr[(c < 2) ? 0 : 3];
        const float* kv = pr[((c & 1) == 0) ? 1 : 4];
        float d = 0.f;
        for (int x = 0; x < SAT_DK; x++) d += qv[h*32+x]*kv[h*32+x];
        sconst[((size_t)s*8 + h)*4 + c] = d * 0.17677669529663687f;
    }
}

// ---------------------------------------------------------------- SAT main (per token, bf16 io)
__global__ __launch_bounds__(256) void sat_attn_kernel(
    const bf16* __restrict__ qkv0, const float* __restrict__ proj,
    const float* __restrict__ sconst, bf16* __restrict__ osum)
{
    int b = blockIdx.x;
    int s = b & 15;
    __shared__ float pr[6][SAT_D];
    __shared__ float sc[8][4];
    for (int i = threadIdx.x; i < 6*SAT_D; i += 256) pr[i >> 8][i & 255] = proj[(size_t)s*6*SAT_D + i];
    if (threadIdx.x < 32) sc[threadIdx.x >> 2][threadIdx.x & 3] = sconst[(size_t)s*32 + threadIdx.x];
    __syncthreads();
    int t = threadIdx.x;
    if (t >= NTOK) return;
    size_t m = (size_t)b*NTOK + t;
    const ushort* q0 = (const ushort*)(qkv0 + m*768);
    const ushort* k0 = q0 + 256;
    const ushort* v0 = q0 + 512;
    const float inv = 0.17677669529663687f;
    for (int h = 0; h < SAT_H; h++) {
        int d0 = h*32;
        float S00=0,S01=0,S02=0,S10=0,S20=0;
        #pragma unroll 8
        for (int d = 0; d < 32; d++) {
            float qv = bf2f(q0[d0+d]), kv = bf2f(k0[d0+d]);
            S00 += qv*kv;
            S01 += qv*pr[1][d0+d];
            S02 += qv*pr[4][d0+d];
            S10 += pr[0][d0+d]*kv;
            S20 += pr[3][d0+d]*kv;
        }
        S00*=inv; S01*=inv; S02*=inv; S10*=inv; S20*=inv;
        float al=0.f, be=0.f, ga=0.f;
        {
            float mx = fmaxf(S00, fmaxf(S01, S02));
            float e0 = expf(S00-mx), e1 = expf(S01-mx), e2 = expf(S02-mx);
            float is = 1.0f/(e0+e1+e2); al += e0*is; be += e1*is; ga += e2*is;
        }
        {
            float a1 = sc[h][0], a2 = sc[h][1];
            float mx = fmaxf(S10, fmaxf(a1, a2));
            float e0 = expf(S10-mx), e1 = expf(a1-mx), e2 = expf(a2-mx);
            float is = 1.0f/(e0+e1+e2); al += e0*is; be += e1*is; ga += e2*is;
        }
        {
            float a1 = sc[h][2], a2 = sc[h][3];
            float mx = fmaxf(S20, fmaxf(a1, a2));
            float e0 = expf(S20-mx), e1 = expf(a1-mx), e2 = expf(a2-mx);
            float is = 1.0f/(e0+e1+e2); al += e0*is; be += e1*is; ga += e2*is;
        }
        #pragma unroll 8
        for (int d = 0; d < 32; d++)
            osum[m*SAT_D + d0 + d] = __float2bfloat16(al*bf2f(v0[d0+d]) + be*pr[2][d0+d] + ga*pr[5][d0+d]);
    }
}

// ---------------------------------------------------------------- ViT attention: full MFMA
__global__ __launch_bounds__(256) void vit_attn_mfma(
    const bf16* __restrict__ qkv, const bf16* __restrict__ vT, bf16* __restrict__ hout)
{
    __shared__ ushort Ks[208*72];
    __shared__ ushort Vt[64*KPV];
    __shared__ ushort Pl[4][16*KPV];

    int u = (blockIdx.x & 7)*96 + (blockIdx.x >> 3);   // XCD-chunked: 8 crops per XCD
    int qg = u & 3, hd = (u >> 2) % 3, b = u / 12;
    int tid = threadIdx.x;
    size_t rowQ = (size_t)b*NTOK;

    for (int i = tid; i < 208*8; i += 256) {
        int k = i >> 3, c = i & 7;
        uint4 v = make_uint4(0u,0u,0u,0u);
        if (k < NTOK) v = *(const uint4*)(qkv + (rowQ + k)*384 + 192 + hd*64 + c*8);
        *(uint4*)&Ks[(size_t)k*72 + c*8] = v;
    }
    {
        const uint4* vsrc = (const uint4*)(vT + (size_t)((b*3 + hd)*64)*KPV);
        uint4* vdst = (uint4*)Vt;
        for (int i = tid; i < 64*KPV/8; i += 256) vdst[i] = vsrc[i];
    }
    __syncthreads();

    int wave = tid >> 6, lane = tid & 63;
    int qstart = (13*qg + 3) >> 2;
    int qcnt   = ((13*(qg+1) + 3) >> 2) - qstart;
    if (wave >= qcnt) return;
    int q0 = (qstart + wave)*16;
    int qcol = lane & 15, g = lane >> 4;

    bf16x8 qf[2] = {};
    if (q0 + qcol < NTOK) {
        const bf16* qp = qkv + (rowQ + q0 + qcol)*384 + hd*64 + g*8;
        qf[0] = *(const bf16x8*)qp;
        qf[1] = *(const bf16x8*)(qp + 32);
    }

    f32x4 st[13] = {};
    #pragma unroll
    for (int t = 0; t < 13; t++) {
        const ushort* krow = &Ks[(size_t)(16*t + qcol)*72];
        bf16x8 a0 = *(const bf16x8*)(krow + g*8);
        bf16x8 a1 = *(const bf16x8*)(krow + 32 + g*8);
        st[t] = __builtin_amdgcn_mfma_f32_16x16x32_bf16(a0, qf[0], st[t], 0, 0, 0);
        st[t] = __builtin_amdgcn_mfma_f32_16x16x32_bf16(a1, qf[1], st[t], 0, 0, 0);
    }

    const float scale = 0.125f;
    float mx = -1e30f;
    #pragma unroll
    for (int t = 0; t < 13; t++)
        #pragma unroll
        for (int r = 0; r < 4; r++) {
            int key = 16*t + 4*g + r;
            float s = st[t][r]*scale;
            st[t][r] = s;
            if (key < NTOK) mx = fmaxf(mx, s);
        }
    mx = fmaxf(mx, __shfl_xor(mx, 16));
    mx = fmaxf(mx, __shfl_xor(mx, 32));
    float sum = 0.f;
    #pragma unroll
    for (int t = 0; t < 13; t++)
        #pragma unroll
        for (int r = 0; r < 4; r++) {
            int key = 16*t + 4*g + r;
            float e = (key < NTOK) ? __expf(st[t][r] - mx) : 0.f;
            st[t][r] = e; sum += e;
        }
    sum += __shfl_xor(sum, 16);
    sum += __shfl_xor(sum, 32);
    float isv = 1.f/sum;

    ushort* P = Pl[wave];
    #pragma unroll
    for (int t = 0; t < 13; t++)
        #pragma unroll
        for (int r = 0; r < 4; r++)
            P[(size_t)qcol*KPV + 16*t + 4*g + r] = f2bf(st[t][r]*isv);
    #pragma unroll
    for (int r = 0; r < 4; r++)
        P[(size_t)qcol*KPV + 208 + 4*g + r] = 0;

    f32x4 oacc[4] = {};
    #pragma unroll
    for (int ks = 0; ks < 7; ks++) {
        bf16x8 pf = *(const bf16x8*)&P[(size_t)qcol*KPV + ks*32 + g*8];
        #pragma unroll
        for (int dt = 0; dt < 4; dt++) {
            bf16x8 vf = *(const bf16x8*)&Vt[(size_t)(dt*16 + qcol)*KPV + ks*32 + g*8];
            oacc[dt] = __builtin_amdgcn_mfma_f32_16x16x32_bf16(pf, vf, oacc[dt], 0, 0, 0);
        }
    }

    int nq = NTOK - q0; if (nq > 16) nq = 16;
    #pragma unroll
    for (int dt = 0; dt < 4; dt++)
        #pragma unroll
        for (int r = 0; r < 4; r++) {
            int q = 4*g + r;
            if (q < nq)
                hout[(rowQ + q0 + q)*EMB + hd*64 + dt*16 + qcol] = __float2bfloat16(oacc[dt][r]);
        }
}

// ---------------------------------------------------------------- final LN on t=0 rows only
__global__ __launch_bounds__(64) void final_ln_kernel(const float* __restrict__ tok,
    const float* __restrict__ w, const float* __restrict__ b_, float* __restrict__ out)
{
    int b = blockIdx.x, lane = threadIdx.x;
    const float* x = tok + (size_t)b*NTOK*EMB;
    float x0 = x[lane], x1 = x[lane+64], x2 = x[lane+128];
    float s = x0+x1+x2;
    for (int o = 32; o > 0; o >>= 1) s += __shfl_xor(s, o);
    float mu = s * (1.0f/EMB);
    float d0 = x0-mu, d1 = x1-mu, d2 = x2-mu;
    float ss = d0*d0 + d1*d1 + d2*d2;
    for (int o = 32; o > 0; o >>= 1) ss += __shfl_xor(ss, o);
    float rs = rsqrtf(ss*(1.0f/EMB) + 1e-5f);
    out[(size_t)b*EMB + lane]     = d0*rs*w[lane]     + b_[lane];
    out[(size_t)b*EMB + lane+64]  = d1*rs*w[lane+64]  + b_[lane+64];
    out[(size_t)b*EMB + lane+128] = d2*rs*w[lane+128] + b_[lane+128];
}

// ---------------------------------------------------------------- launch
extern "C" void kernel_launch(void* const* d_in, const int* in_sizes, int n_in,
                              void* d_out, int out_size, void* d_ws, size_t ws_size,
                              hipStream_t stream)
{
    const float* x          = (const float*)d_in[0];
    const float* xg         = (const float*)d_in[1];
    const float* per_li     = (const float*)d_in[2];
    const float* per_li_var = (const float*)d_in[3];
    const float* patch_w    = (const float*)d_in[4];
    const float* patch_b    = (const float*)d_in[5];
    const float* cls_token  = (const float*)d_in[6];
    const float* pos_embed  = (const float*)d_in[7];
    const float* eleva      = (const float*)d_in[8];
    const float* eleva_var  = (const float*)d_in[9];
    const float* sat_wq     = (const float*)d_in[10];
    const float* sat_bq     = (const float*)d_in[11];
    const float* sat_wk     = (const float*)d_in[12];
    const float* sat_bk     = (const float*)d_in[13];
    const float* sat_wv     = (const float*)d_in[14];
    const float* sat_bv     = (const float*)d_in[15];
    const float* sat_wo     = (const float*)d_in[16];
    const float* sat_bo     = (const float*)d_in[17];
    const float* ln1_w      = (const float*)d_in[18];
    const float* ln1_b      = (const float*)d_in[19];
    const float* qkv_w      = (const float*)d_in[20];
    const float* proj_w     = (const float*)d_in[21];
    const float* proj_b     = (const float*)d_in[22];
    const float* ln2_w      = (const float*)d_in[23];
    const float* ln2_b      = (const float*)d_in[24];
    const float* fc1_w      = (const float*)d_in[25];
    const float* fc1_b      = (const float*)d_in[26];
    const float* fc2_w      = (const float*)d_in[27];
    const float* fc2_b      = (const float*)d_in[28];
    const float* lnf_w      = (const float*)d_in[29];
    const float* lnf_b      = (const float*)d_in[30];
    float* out = (float*)d_out;

    char* p = (char*)d_ws;
    float* tokf = (float*)p;                 p += (size_t)M_TOK*EMB*4;
    bf16* hb    = (bf16*)p;                  p += (size_t)M_TOK*EMB*2;
    bf16* tokb  = (bf16*)p;                  p += (size_t)M_TOK*EMB*2;
    bf16* qkvb  = (bf16*)p;                  p += (size_t)M_TOK*768*2;
    bf16* osum  = (bf16*)p;                  p += (size_t)M_TOK*SAT_D*2;
    bf16* vTb   = (bf16*)p;                  p += (size_t)NB*3*64*KPV*2;
    bf16* qkv_wt  = (bf16*)p;                p += (size_t)DEPTH*576*EMB*2;
    bf16* proj_wt = (bf16*)p;                p += (size_t)DEPTH*EMB*EMB*2;
    bf16* fc1_wt  = (bf16*)p;                p += (size_t)DEPTH*MLPD*EMB*2;
    bf16* fc2_wt  = (bf16*)p;                p += (size_t)DEPTH*EMB*MLPD*2;
    bf16* patch_wb= (bf16*)p;                p += (size_t)EMB*768*2;
    bf16* sat_wqkvt = (bf16*)p;              p += (size_t)3*SAT_D*EMB*2;   // [768][192]
    bf16* sat_wot = (bf16*)p;                p += (size_t)EMB*SAT_D*2;
    float* sat_bqkv = (float*)p;             p += 768*4;
    float* projb  = (float*)p;               p += 16*6*SAT_D*4;
    float* sconst = (float*)p;               p += 16*32*4;
    double* statp = (double*)p;              p += 256*2*8;
    int*   idxb   = (int*)p;

    // ---- weight prep (merged) ----
    prep_transpose_kernel<<<5376, 256, 0, stream>>>(
        qkv_w, proj_w, fc1_w, fc2_w, sat_wq, sat_wk, sat_wv, sat_wo,
        qkv_wt, proj_wt, fc1_wt, fc2_wt, sat_wqkvt, sat_wot);
    concat3_kernel<<<3, 256, 0, stream>>>(sat_bq, sat_bk, sat_bv, sat_bqkv);
    cast_kernel<<<(EMB*768 + 255)/256, 256, 0, stream>>>(patch_w, patch_wb, EMB*768);

    // ---- elevation stats (2-stage) ----
    stats1_kernel<<<dim3(16, 16), 256, 0, stream>>>(xg, statp);
    stats2_kernel<<<16, 64, 0, stream>>>(statp, per_li, per_li_var, idxb);
    // ---- patch embed ----
    im2col_kernel<<<(M_PATCH*768 + 255)/256, 256, 0, stream>>>(x, qkvb);
    mfma_gemm<4,true,3><<<dim3(EMB/64, M_PATCH/64), 256, 0, stream>>>(
        qkvb, patch_wb, patch_b, pos_embed, tokb, M_PATCH, EMB, 768, EMB, 1.0f);
    cls_kernel<<<(NB*EMB + 255)/256, 256, 0, stream>>>(cls_token, pos_embed, tokb);
    // ---- SAT ----
    sat_rows_kernel<<<16, 256, 0, stream>>>(eleva, eleva_var, sat_wq, sat_bq, sat_wk, sat_bk,
                                            sat_wv, sat_bv, idxb, projb, sconst);
    mfma_gemm<1,true,3><<<dim3(768/64, M_TOK/64), 256, 0, stream>>>(
        tokb, sat_wqkvt, sat_bqkv, nullptr, qkvb, M_TOK, 768, EMB, 768, 1.0f);
    sat_attn_kernel<<<NB, 256, 0, stream>>>(qkvb, projb, sconst, osum);
    // SAT output projection + first ln1, fused
    mfma_gemm_ln<false><<<M_TOK/16, 256, 0, stream>>>(
        osum, sat_wot, sat_bo, 3.0f, ln1_w, ln1_b, tokf, hb, SAT_D);
    // ---- ViT blocks ----
    for (int i = 0; i < DEPTH; i++) {
        // merged QK-proj + V^T-proj
        qkv_proj_kernel<<<1773, 256, 0, stream>>>(
            hb, qkv_wt + (size_t)i*576*EMB, qkv_wt + ((size_t)i*576 + 384)*EMB, qkvb, vTb);
        vit_attn_mfma<<<768, 256, 0, stream>>>(qkvb, vTb, hb);
        // attn out proj + residual + ln2, fused
        mfma_gemm_ln<true><<<M_TOK/16, 256, 0, stream>>>(
            hb, proj_wt + (size_t)i*EMB*EMB, proj_b + i*EMB, 1.0f,
            ln2_w + i*EMB, ln2_b + i*EMB, tokf, hb, EMB);
        // fc1 + gelu
        mfma_gemm<3,true,3><<<dim3(MLPD/64, M_TOK/64), 256, 0, stream>>>(
            hb, fc1_wt + (size_t)i*MLPD*EMB, fc1_b + i*MLPD, nullptr, qkvb, M_TOK, MLPD, EMB, MLPD, 1.0f);
        if (i < DEPTH-1) {
            // fc2 + residual + next layer's ln1, fused
            mfma_gemm_ln<true><<<M_TOK/16, 256, 0, stream>>>(
                qkvb, fc2_wt + (size_t)i*EMB*MLPD, fc2_b + i*EMB, 1.0f,
                ln1_w + (i+1)*EMB, ln1_b + (i+1)*EMB, tokf, hb, MLPD);
        } else {
            mfma_gemm<2,false,3><<<dim3(EMB/64, M_TOK/64), 256, 0, stream>>>(
                qkvb, fc2_wt + (size_t)i*EMB*MLPD, fc2_b + i*EMB, nullptr, tokf, M_TOK, EMB, MLPD, EMB, 1.0f);
        }
    }
    final_ln_kernel<<<NB, 64, 0, stream>>>(tokf, lnf_w, lnf_b, out);
}